// Round 1
// baseline (1123.577 us; speedup 1.0000x reference)
//
#include <hip/hip_runtime.h>
#include <math.h>

#define B_ 32
#define P_ 2048
#define N_ 65536
#define K_ 16
#define L_ 8
#define F_ 64
#define KS_ 5
#define KS3_ 125
#define NC_ 40
#define H_ 256
#define EPS_ 1e-5f

// ---------------- Kernel 1: KNN (per batch, 2048 pts, top-16) ----------------
__global__ __launch_bounds__(256) void knn_kernel(const float* __restrict__ pos,
                                                  int* __restrict__ nbr) {
    __shared__ float sx[P_], sy[P_], sz[P_], sq[P_];
    int b = blockIdx.x >> 3;       // 8 tiles per batch
    int tile = blockIdx.x & 7;
    int base = b * P_;
    for (int j = threadIdx.x; j < P_; j += 256) {
        float x = pos[(base + j) * 3 + 0];
        float y = pos[(base + j) * 3 + 1];
        float z = pos[(base + j) * 3 + 2];
        sx[j] = x; sy[j] = y; sz[j] = z; sq[j] = x * x + y * y + z * z;
    }
    __syncthreads();
    int il = tile * 256 + threadIdx.x;
    float qx = sx[il], qy = sy[il], qz = sz[il], qs = sq[il];
    float bd[K_]; int bi[K_];
#pragma unroll
    for (int m = 0; m < K_; m++) { bd[m] = INFINITY; bi[m] = 0; }
    for (int j = 0; j < P_; j++) {
        float d = qs + sq[j] - 2.f * (qx * sx[j] + qy * sy[j] + qz * sz[j]);
        if (j == il) continue;
        if (d < bd[K_ - 1]) {
            // static-index bubble insertion (keeps arrays in VGPRs)
            float cd = d; int ci = j;
#pragma unroll
            for (int m = 0; m < K_; m++) {
                bool sw = cd < bd[m];
                float td = sw ? bd[m] : cd;
                int   ti = sw ? bi[m] : ci;
                bd[m] = sw ? cd : bd[m];
                bi[m] = sw ? ci : bi[m];
                cd = td; ci = ti;
            }
        }
    }
    // layout [K][N] for coalesced writes / reads
#pragma unroll
    for (int m = 0; m < K_; m++) nbr[m * N_ + base + il] = base + bi[m];
}

// ------------- Kernel 2: cov + 5x QR (LAPACK Householder) + dc ---------------
__global__ __launch_bounds__(256) void geom_kernel(const float* __restrict__ pos,
                                                   const int* __restrict__ nbr,
                                                   float* __restrict__ dcn) {
    int i = blockIdx.x * 256 + threadIdx.x;
    float px = pos[i * 3 + 0], py = pos[i * 3 + 1], pz = pos[i * 3 + 2];
    float cx[K_], cy[K_], cz[K_];
#pragma unroll
    for (int k = 0; k < K_; k++) {
        int n = nbr[k * N_ + i];
        cx[k] = pos[n * 3 + 0] - px;
        cy[k] = pos[n * 3 + 1] - py;
        cz[k] = pos[n * 3 + 2] - pz;
    }
    // covariance over first L=8 neighbors
    float A[3][3];
    {
        float a00 = 0, a01 = 0, a02 = 0, a11 = 0, a12 = 0, a22 = 0;
#pragma unroll
        for (int l = 0; l < L_; l++) {
            a00 += cx[l] * cx[l]; a01 += cx[l] * cy[l]; a02 += cx[l] * cz[l];
            a11 += cy[l] * cy[l]; a12 += cy[l] * cz[l]; a22 += cz[l] * cz[l];
        }
        A[0][0] = a00; A[0][1] = a01; A[0][2] = a02;
        A[1][0] = a01; A[1][1] = a11; A[1][2] = a12;
        A[2][0] = a02; A[2][1] = a12; A[2][2] = a22;
    }
    float Vt[3][3] = {{1.f, 0.f, 0.f}, {0.f, 1.f, 0.f}, {0.f, 0.f, 1.f}};

    for (int it = 0; it < 5; it++) {
        float M00 = A[0][0], M01 = A[0][1], M02 = A[0][2];
        float M10 = A[1][0], M11 = A[1][1], M12 = A[1][2];
        float M20 = A[2][0], M21 = A[2][1], M22 = A[2][2];
        // --- Householder col 0 (LAPACK dlarfg convention) ---
        float tau0 = 0.f, v1 = 0.f, v2 = 0.f;
        float xn2 = M10 * M10 + M20 * M20;
        if (xn2 != 0.f) {
            float beta = -copysignf(sqrtf(M00 * M00 + xn2), M00);
            tau0 = (beta - M00) / beta;
            float inv = 1.f / (M00 - beta);
            v1 = M10 * inv; v2 = M20 * inv;
            float s;
            s = tau0 * (M01 + v1 * M11 + v2 * M21); M01 -= s; M11 -= v1 * s; M21 -= v2 * s;
            s = tau0 * (M02 + v1 * M12 + v2 * M22); M02 -= s; M12 -= v1 * s; M22 -= v2 * s;
            M00 = beta;
        }
        // --- Householder col 1 ---
        float tau1 = 0.f, u2 = 0.f;
        if (M21 != 0.f) {
            float beta1 = -copysignf(sqrtf(M11 * M11 + M21 * M21), M11);
            tau1 = (beta1 - M11) / beta1;
            u2 = M21 / (M11 - beta1);
            float s = tau1 * (M12 + u2 * M22); M12 -= s; M22 -= u2 * s;
            M11 = beta1;
        }
        // --- Q = H0 * H1 ---
        float h11 = 1.f - tau1, h12 = -tau1 * u2, h22 = 1.f - tau1 * u2 * u2;
        float Q[3][3];
        Q[0][0] = 1.f - tau0;
        Q[1][0] = -v1 * tau0;
        Q[2][0] = -v2 * tau0;
        float t1 = tau0 * (v1 * h11 + v2 * h12);
        Q[0][1] = -t1;
        Q[1][1] = h11 - v1 * t1;
        Q[2][1] = h12 - v2 * t1;
        float t2 = tau0 * (v1 * h12 + v2 * h22);
        Q[0][2] = -t2;
        Q[1][2] = h12 - v1 * t2;
        Q[2][2] = h22 - v2 * t2;
        // --- A = R @ Q (R upper triangular) ---
        A[0][0] = M00 * Q[0][0] + M01 * Q[1][0] + M02 * Q[2][0];
        A[0][1] = M00 * Q[0][1] + M01 * Q[1][1] + M02 * Q[2][1];
        A[0][2] = M00 * Q[0][2] + M01 * Q[1][2] + M02 * Q[2][2];
        A[1][0] = M11 * Q[1][0] + M12 * Q[2][0];
        A[1][1] = M11 * Q[1][1] + M12 * Q[2][1];
        A[1][2] = M11 * Q[1][2] + M12 * Q[2][2];
        A[2][0] = M22 * Q[2][0];
        A[2][1] = M22 * Q[2][1];
        A[2][2] = M22 * Q[2][2];
        // --- Vt = Vt @ Q ---
        float nv[3][3];
#pragma unroll
        for (int r = 0; r < 3; r++)
#pragma unroll
            for (int c = 0; c < 3; c++)
                nv[r][c] = Vt[r][0] * Q[0][c] + Vt[r][1] * Q[1][c] + Vt[r][2] * Q[2][c];
#pragma unroll
        for (int r = 0; r < 3; r++)
#pragma unroll
            for (int c = 0; c < 3; c++) Vt[r][c] = nv[r][c];
    }

    // dc = clusters @ Vt ; pass 1: z-column sum + per-column abs-max
    float s2 = 0.f, mx01 = 0.f, mx2 = 0.f;
#pragma unroll
    for (int k = 0; k < K_; k++) {
        float d0 = cx[k] * Vt[0][0] + cy[k] * Vt[1][0] + cz[k] * Vt[2][0];
        float d1 = cx[k] * Vt[0][1] + cy[k] * Vt[1][1] + cz[k] * Vt[2][1];
        float d2 = cx[k] * Vt[0][2] + cy[k] * Vt[1][2] + cz[k] * Vt[2][2];
        s2 += d2;
        mx01 = fmaxf(mx01, fmaxf(fabsf(d0), fabsf(d1)));
        mx2  = fmaxf(mx2, fabsf(d2));
    }
    float sg = (s2 > 0.f) ? 1.f : ((s2 < 0.f) ? -1.f : 0.f);
    float mx = fmaxf(mx01, (sg == 0.f) ? 0.f : mx2);
    float hs = 0.5f / mx;
    // pass 2: recompute, normalize, write layout [K][3][N]
#pragma unroll
    for (int k = 0; k < K_; k++) {
        float d0 = cx[k] * Vt[0][0] + cy[k] * Vt[1][0] + cz[k] * Vt[2][0];
        float d1 = cx[k] * Vt[0][1] + cy[k] * Vt[1][1] + cz[k] * Vt[2][1];
        float d2 = (cx[k] * Vt[0][2] + cy[k] * Vt[1][2] + cz[k] * Vt[2][2]) * sg;
        dcn[(k * 3 + 0) * N_ + i] = d0 * hs + 0.5f;
        dcn[(k * 3 + 1) * N_ + i] = d1 * hs + 0.5f;
        dcn[(k * 3 + 2) * N_ + i] = d2 * hs + 0.5f;
    }
}

// ---------- Kernel 3: trilinear spline gather + out_nondir + BN partials -----
__global__ __launch_bounds__(256) void spline_kernel(const float* __restrict__ dcn,
                                                     const float* __restrict__ w_spline,
                                                     const float* __restrict__ w_root,
                                                     const float* __restrict__ b_spline,
                                                     float* __restrict__ x,
                                                     float* __restrict__ partials) {
    __shared__ float ws[KS3_ * F_];
    __shared__ float red[4][64];
    for (int t = threadIdx.x; t < KS3_ * F_; t += 256) ws[t] = w_spline[t];
    __syncthreads();
    int wave = threadIdx.x >> 6, f = threadIdx.x & 63;
    float wr = w_root[f] + b_spline[f];
    float s1 = 0.f, s2 = 0.f;
    for (int p = 0; p < 16; p++) {
        int i = blockIdx.x * 64 + wave * 16 + p;
        float acc = 0.f;
#pragma unroll
        for (int k = 0; k < K_; k++) {
            float p0 = dcn[(k * 3 + 0) * N_ + i] * 4.f;
            float p1 = dcn[(k * 3 + 1) * N_ + i] * 4.f;
            float p2 = dcn[(k * 3 + 2) * N_ + i] * 4.f;
            float i0 = fminf(fmaxf(floorf(p0), 0.f), 3.f);
            float i1 = fminf(fmaxf(floorf(p1), 0.f), 3.f);
            float i2 = fminf(fmaxf(floorf(p2), 0.f), 3.f);
            float f0 = p0 - i0, f1 = p1 - i1, f2 = p2 - i2;
            float g0 = 1.f - f0, g1 = 1.f - f1, g2 = 1.f - f2;
            int base = (int)i0 + 5 * (int)i1 + 25 * (int)i2;
            const float* w0 = &ws[base * 64 + f];
            acc += (g0 * g1 * g2) * w0[0];
            acc += (f0 * g1 * g2) * w0[64];
            acc += (g0 * f1 * g2) * w0[5 * 64];
            acc += (f0 * f1 * g2) * w0[6 * 64];
            acc += (g0 * g1 * f2) * w0[25 * 64];
            acc += (f0 * g1 * f2) * w0[26 * 64];
            acc += (g0 * f1 * f2) * w0[30 * 64];
            acc += (f0 * f1 * f2) * w0[31 * 64];
        }
        float xv = acc * (1.f / 16.f) + wr;
        x[i * 64 + f] = xv;
        s1 += xv; s2 += xv * xv;
    }
    red[wave][f] = s1; __syncthreads();
    if (threadIdx.x < 64)
        partials[blockIdx.x * 128 + f] = red[0][f] + red[1][f] + red[2][f] + red[3][f];
    __syncthreads();
    red[wave][f] = s2; __syncthreads();
    if (threadIdx.x < 64)
        partials[blockIdx.x * 128 + 64 + f] = red[0][f] + red[1][f] + red[2][f] + red[3][f];
}

// ----------------------- Kernel 4: BN stats finalize -------------------------
__global__ void stats_kernel(const float* __restrict__ partials,
                             const float* __restrict__ gamma,
                             const float* __restrict__ beta,
                             float* __restrict__ stats) {
    int f = threadIdx.x;
    if (f < 64) {
        double s1 = 0.0, s2 = 0.0;
        for (int b = 0; b < 1024; b++) {
            s1 += (double)partials[b * 128 + f];
            s2 += (double)partials[b * 128 + 64 + f];
        }
        double mu = s1 / (double)N_;
        double var = s2 / (double)N_ - mu * mu;
        double scale = (double)gamma[f] / sqrt(var + (double)EPS_);
        double shift = (double)beta[f] - mu * scale;
        stats[f] = (float)scale;
        stats[64 + f] = (float)shift;
    }
}

// -------------- Kernel 5a: sigmoid + per-batch-chunk partial pool ------------
__global__ __launch_bounds__(256) void pool_partial_kernel(const float* __restrict__ x,
                                                           const float* __restrict__ stats,
                                                           float* __restrict__ pp) {
    __shared__ float red[4][64];
    int blk = blockIdx.x;            // 32 batches * 8 chunks
    int b = blk >> 3, ch = blk & 7;
    int f = threadIdx.x & 63, w = threadIdx.x >> 6;
    float scale = stats[f], shift = stats[64 + f];
    float acc = 0.f;
    int row0 = b * P_ + ch * 256;
    for (int r = w; r < 256; r += 4) {
        float v = x[(row0 + r) * 64 + f];
        float t = v * scale + shift;
        acc += 1.f / (1.f + expf(-t));
    }
    red[w][f] = acc; __syncthreads();
    if (threadIdx.x < 64) pp[blk * 64 + f] = red[0][f] + red[1][f] + red[2][f] + red[3][f];
}

// ---------------------- Kernel 5b: finalize batch means ----------------------
__global__ void pool_final_kernel(const float* __restrict__ pp, float* __restrict__ ys) {
    for (int idx = threadIdx.x; idx < B_ * 64; idx += 256) {
        int b = idx >> 6, f = idx & 63;
        float s = 0.f;
#pragma unroll
        for (int g = 0; g < 8; g++) s += pp[(b * 8 + g) * 64 + f];
        ys[idx] = s * (1.f / 2048.f);
    }
}

// -------------------- Kernel 6: MLP + log_softmax (1 block) ------------------
__global__ __launch_bounds__(256) void mlp_kernel(const float* __restrict__ ys,
                                                  const float* __restrict__ w1,
                                                  const float* __restrict__ b1,
                                                  const float* __restrict__ w2,
                                                  const float* __restrict__ b2,
                                                  float* __restrict__ out) {
    __shared__ float sy[B_ * F_];
    __shared__ float sy1[B_ * H_];
    __shared__ float sy2[B_ * NC_];
    for (int t = threadIdx.x; t < B_ * F_; t += 256) sy[t] = ys[t];
    __syncthreads();
    for (int idx = threadIdx.x; idx < B_ * H_; idx += 256) {
        int b = idx >> 8, j = idx & 255;
        float acc = b1[j];
#pragma unroll 8
        for (int c = 0; c < F_; c++) acc += sy[b * 64 + c] * w1[c * 256 + j];
        sy1[idx] = acc > 0.f ? acc : expm1f(acc);
    }
    __syncthreads();
    for (int idx = threadIdx.x; idx < B_ * NC_; idx += 256) {
        int b = idx / NC_, j = idx % NC_;
        float acc = b2[j];
#pragma unroll 8
        for (int c = 0; c < H_; c++) acc += sy1[b * 256 + c] * w2[c * 40 + j];
        sy2[idx] = acc;
    }
    __syncthreads();
    if (threadIdx.x < B_) {
        int b = threadIdx.x;
        float m = -INFINITY;
        for (int j = 0; j < NC_; j++) m = fmaxf(m, sy2[b * NC_ + j]);
        float s = 0.f;
        for (int j = 0; j < NC_; j++) s += expf(sy2[b * NC_ + j] - m);
        float lse = logf(s);
        for (int j = 0; j < NC_; j++) out[b * NC_ + j] = sy2[b * NC_ + j] - m - lse;
    }
}

extern "C" void kernel_launch(void* const* d_in, const int* in_sizes, int n_in,
                              void* d_out, int out_size, void* d_ws, size_t ws_size,
                              hipStream_t stream) {
    const float* pos      = (const float*)d_in[0];
    const float* w_spline = (const float*)d_in[2];
    const float* w_root   = (const float*)d_in[3];
    const float* b_spline = (const float*)d_in[4];
    const float* bn_gamma = (const float*)d_in[5];
    const float* bn_beta  = (const float*)d_in[6];
    const float* w1       = (const float*)d_in[7];
    const float* b1       = (const float*)d_in[8];
    const float* w2       = (const float*)d_in[9];
    const float* b2       = (const float*)d_in[10];
    float* out = (float*)d_out;

    char* ws = (char*)d_ws;
    int*   nbr      = (int*)(ws + 0);                      // 4 MB
    float* dcn      = (float*)(ws + (4u << 20));           // 12 MB
    float* x        = (float*)(ws + (16u << 20));          // 16 MB
    float* partials = (float*)(ws + (32u << 20));          // 512 KB
    float* stats    = (float*)(ws + (32u << 20) + (512u << 10));        // 512 B
    float* pp       = (float*)(ws + (32u << 20) + (512u << 10) + 4096); // 64 KB
    float* ys       = (float*)(ws + (32u << 20) + (512u << 10) + 4096 + (64u << 10)); // 8 KB

    knn_kernel<<<B_ * 8, 256, 0, stream>>>(pos, nbr);
    geom_kernel<<<N_ / 256, 256, 0, stream>>>(pos, nbr, dcn);
    spline_kernel<<<N_ / 64, 256, 0, stream>>>(dcn, w_spline, w_root, b_spline, x, partials);
    stats_kernel<<<1, 64, 0, stream>>>(partials, bn_gamma, bn_beta, stats);
    pool_partial_kernel<<<B_ * 8, 256, 0, stream>>>(x, stats, pp);
    pool_final_kernel<<<1, 256, 0, stream>>>(pp, ys);
    mlp_kernel<<<1, 256, 0, stream>>>(ys, w1, b1, w2, b2, out);
}

// Round 2
// 535.797 us; speedup vs baseline: 2.0970x; 2.0970x over previous
//
#include <hip/hip_runtime.h>
#include <math.h>

#define B_ 32
#define P_ 2048
#define N_ 65536
#define K_ 16
#define L_ 8
#define F_ 64
#define KS_ 5
#define KS3_ 125
#define NC_ 40
#define H_ 256
#define EPS_ 1e-5f

// exact same fp expression used in scan and merge (pinned fmaf order)
__device__ __forceinline__ float distf(float4 C, float nx, float ny, float nz, float qs) {
    return fmaf(C.x, nx, fmaf(C.y, ny, fmaf(C.z, nz, C.w))) + qs;
}

// static-index sorted insertion (stays in VGPRs)
__device__ __forceinline__ void insert16(float (&bd)[16], int (&bi)[16], float cd, int ci) {
#pragma unroll
    for (int m = 0; m < 16; m++) {
        bool sw = cd < bd[m];
        float td = sw ? bd[m] : cd;
        int   ti = sw ? bi[m] : ci;
        bd[m] = sw ? cd : bd[m];
        bi[m] = sw ? ci : bi[m];
        cd = td; ci = ti;
    }
}

// ---------------- Kernel 1: KNN (4 segments/query in-block + merge) ----------
__global__ __launch_bounds__(1024) void knn_kernel(const float* __restrict__ pos,
                                                   int* __restrict__ nbr) {
    __shared__ float4 cloud[P_];                 // 32 KB
    __shared__ unsigned short lists[1024 * 16];  // 32 KB, [seg][q][16]
    int b = blockIdx.x >> 3, tile = blockIdx.x & 7;
    int base = b * P_;
    int t = threadIdx.x;
    for (int j = t; j < P_; j += 1024) {
        float x = pos[(base + j) * 3 + 0];
        float y = pos[(base + j) * 3 + 1];
        float z = pos[(base + j) * 3 + 2];
        cloud[j] = make_float4(x, y, z, x * x + y * y + z * z);
    }
    __syncthreads();

    int seg = t >> 8, q = t & 255;
    int il = tile * 256 + q;
    float4 Q = cloud[il];
    float nx = -2.f * Q.x, ny = -2.f * Q.y, nz = -2.f * Q.z, qs = Q.w;

    float bd[16]; int bi[16];
#pragma unroll
    for (int m = 0; m < 16; m++) { bd[m] = INFINITY; bi[m] = 0; }
    float e0d = INFINITY, e1d = INFINITY;
    int   e0i = 0,        e1i = 0;
    int cnt = 0;
    float thr = INFINITY;                        // stale-but-safe threshold

    int j0 = seg << 9;
    float4 C = cloud[j0];
    for (int jj = 0; jj < 512; jj++) {
        float4 Cn = cloud[j0 + ((jj + 1) & 511)];   // prefetch (wraps, harmless)
        int j = j0 + jj;
        float d = distf(C, nx, ny, nz, qs);
        bool acc = (d < thr) && (j != il);
        // depth-2 shift buffer, all static-indexed
        e1d = acc ? e0d : e1d;  e1i = acc ? e0i : e1i;
        e0d = acc ? d   : e0d;  e0i = acc ? j   : e0i;
        cnt = acc ? cnt + 1 : cnt;
        if (__any(cnt >= 2)) {
            insert16(bd, bi, e1d, e1i);   // e1 is older: keeps ascending-j stability
            insert16(bd, bi, e0d, e0i);
            e0d = INFINITY; e1d = INFINITY; cnt = 0;
            thr = bd[15];
        }
        C = Cn;
    }
    insert16(bd, bi, e1d, e1i);
    insert16(bd, bi, e0d, e0i);

#pragma unroll
    for (int m = 0; m < 16; m++) lists[t * 16 + m] = (unsigned short)bi[m];
    __syncthreads();

    // merge: threads 0..255, one query each; recompute d bit-identically from LDS
    if (t < 256) {
        int il2 = tile * 256 + t;
        float4 Q2 = cloud[il2];
        float nx2 = -2.f * Q2.x, ny2 = -2.f * Q2.y, nz2 = -2.f * Q2.z, qs2 = Q2.w;
        float md[16]; int mi[16];
#pragma unroll
        for (int m = 0; m < 16; m++) { md[m] = INFINITY; mi[m] = 0; }
        for (int s = 0; s < 4; s++) {
#pragma unroll
            for (int r = 0; r < 16; r++) {
                int j = lists[((s << 8) | t) * 16 + r];
                float4 Cm = cloud[j];
                insert16(md, mi, distf(Cm, nx2, ny2, nz2, qs2), j);
            }
        }
#pragma unroll
        for (int m = 0; m < 16; m++) nbr[m * N_ + base + il2] = base + mi[m];
    }
}

// ------------- Kernel 2: cov + 5x QR (LAPACK Householder) + dc ---------------
__global__ __launch_bounds__(256) void geom_kernel(const float* __restrict__ pos,
                                                   const int* __restrict__ nbr,
                                                   float* __restrict__ dcn) {
    int i = blockIdx.x * 256 + threadIdx.x;
    float px = pos[i * 3 + 0], py = pos[i * 3 + 1], pz = pos[i * 3 + 2];
    float cx[K_], cy[K_], cz[K_];
#pragma unroll
    for (int k = 0; k < K_; k++) {
        int n = nbr[k * N_ + i];
        cx[k] = pos[n * 3 + 0] - px;
        cy[k] = pos[n * 3 + 1] - py;
        cz[k] = pos[n * 3 + 2] - pz;
    }
    float A[3][3];
    {
        float a00 = 0, a01 = 0, a02 = 0, a11 = 0, a12 = 0, a22 = 0;
#pragma unroll
        for (int l = 0; l < L_; l++) {
            a00 += cx[l] * cx[l]; a01 += cx[l] * cy[l]; a02 += cx[l] * cz[l];
            a11 += cy[l] * cy[l]; a12 += cy[l] * cz[l]; a22 += cz[l] * cz[l];
        }
        A[0][0] = a00; A[0][1] = a01; A[0][2] = a02;
        A[1][0] = a01; A[1][1] = a11; A[1][2] = a12;
        A[2][0] = a02; A[2][1] = a12; A[2][2] = a22;
    }
    float Vt[3][3] = {{1.f, 0.f, 0.f}, {0.f, 1.f, 0.f}, {0.f, 0.f, 1.f}};

    for (int it = 0; it < 5; it++) {
        float M00 = A[0][0], M01 = A[0][1], M02 = A[0][2];
        float M10 = A[1][0], M11 = A[1][1], M12 = A[1][2];
        float M20 = A[2][0], M21 = A[2][1], M22 = A[2][2];
        float tau0 = 0.f, v1 = 0.f, v2 = 0.f;
        float xn2 = M10 * M10 + M20 * M20;
        if (xn2 != 0.f) {
            float beta = -copysignf(sqrtf(M00 * M00 + xn2), M00);
            tau0 = (beta - M00) / beta;
            float inv = 1.f / (M00 - beta);
            v1 = M10 * inv; v2 = M20 * inv;
            float s;
            s = tau0 * (M01 + v1 * M11 + v2 * M21); M01 -= s; M11 -= v1 * s; M21 -= v2 * s;
            s = tau0 * (M02 + v1 * M12 + v2 * M22); M02 -= s; M12 -= v1 * s; M22 -= v2 * s;
            M00 = beta;
        }
        float tau1 = 0.f, u2 = 0.f;
        if (M21 != 0.f) {
            float beta1 = -copysignf(sqrtf(M11 * M11 + M21 * M21), M11);
            tau1 = (beta1 - M11) / beta1;
            u2 = M21 / (M11 - beta1);
            float s = tau1 * (M12 + u2 * M22); M12 -= s; M22 -= u2 * s;
            M11 = beta1;
        }
        float h11 = 1.f - tau1, h12 = -tau1 * u2, h22 = 1.f - tau1 * u2 * u2;
        float Q[3][3];
        Q[0][0] = 1.f - tau0;
        Q[1][0] = -v1 * tau0;
        Q[2][0] = -v2 * tau0;
        float t1 = tau0 * (v1 * h11 + v2 * h12);
        Q[0][1] = -t1;
        Q[1][1] = h11 - v1 * t1;
        Q[2][1] = h12 - v2 * t1;
        float t2 = tau0 * (v1 * h12 + v2 * h22);
        Q[0][2] = -t2;
        Q[1][2] = h12 - v1 * t2;
        Q[2][2] = h22 - v2 * t2;
        A[0][0] = M00 * Q[0][0] + M01 * Q[1][0] + M02 * Q[2][0];
        A[0][1] = M00 * Q[0][1] + M01 * Q[1][1] + M02 * Q[2][1];
        A[0][2] = M00 * Q[0][2] + M01 * Q[1][2] + M02 * Q[2][2];
        A[1][0] = M11 * Q[1][0] + M12 * Q[2][0];
        A[1][1] = M11 * Q[1][1] + M12 * Q[2][1];
        A[1][2] = M11 * Q[1][2] + M12 * Q[2][2];
        A[2][0] = M22 * Q[2][0];
        A[2][1] = M22 * Q[2][1];
        A[2][2] = M22 * Q[2][2];
        float nv[3][3];
#pragma unroll
        for (int r = 0; r < 3; r++)
#pragma unroll
            for (int c = 0; c < 3; c++)
                nv[r][c] = Vt[r][0] * Q[0][c] + Vt[r][1] * Q[1][c] + Vt[r][2] * Q[2][c];
#pragma unroll
        for (int r = 0; r < 3; r++)
#pragma unroll
            for (int c = 0; c < 3; c++) Vt[r][c] = nv[r][c];
    }

    float s2 = 0.f, mx01 = 0.f, mx2 = 0.f;
#pragma unroll
    for (int k = 0; k < K_; k++) {
        float d0 = cx[k] * Vt[0][0] + cy[k] * Vt[1][0] + cz[k] * Vt[2][0];
        float d1 = cx[k] * Vt[0][1] + cy[k] * Vt[1][1] + cz[k] * Vt[2][1];
        float d2 = cx[k] * Vt[0][2] + cy[k] * Vt[1][2] + cz[k] * Vt[2][2];
        s2 += d2;
        mx01 = fmaxf(mx01, fmaxf(fabsf(d0), fabsf(d1)));
        mx2  = fmaxf(mx2, fabsf(d2));
    }
    float sg = (s2 > 0.f) ? 1.f : ((s2 < 0.f) ? -1.f : 0.f);
    float mx = fmaxf(mx01, (sg == 0.f) ? 0.f : mx2);
    float hs = 0.5f / mx;
#pragma unroll
    for (int k = 0; k < K_; k++) {
        float d0 = cx[k] * Vt[0][0] + cy[k] * Vt[1][0] + cz[k] * Vt[2][0];
        float d1 = cx[k] * Vt[0][1] + cy[k] * Vt[1][1] + cz[k] * Vt[2][1];
        float d2 = (cx[k] * Vt[0][2] + cy[k] * Vt[1][2] + cz[k] * Vt[2][2]) * sg;
        dcn[(k * 3 + 0) * N_ + i] = d0 * hs + 0.5f;
        dcn[(k * 3 + 1) * N_ + i] = d1 * hs + 0.5f;
        dcn[(k * 3 + 2) * N_ + i] = d2 * hs + 0.5f;
    }
}

// ---------- Kernel 3: trilinear spline gather + out_nondir + BN partials -----
__global__ __launch_bounds__(256) void spline_kernel(const float* __restrict__ dcn,
                                                     const float* __restrict__ w_spline,
                                                     const float* __restrict__ w_root,
                                                     const float* __restrict__ b_spline,
                                                     float* __restrict__ x,
                                                     float* __restrict__ partials) {
    __shared__ float ws[KS3_ * F_];
    __shared__ float red[4][64];
    for (int t = threadIdx.x; t < KS3_ * F_; t += 256) ws[t] = w_spline[t];
    __syncthreads();
    int wave = threadIdx.x >> 6, f = threadIdx.x & 63;
    float wr = w_root[f] + b_spline[f];
    float s1 = 0.f, s2 = 0.f;
    for (int p = 0; p < 16; p++) {
        int i = blockIdx.x * 64 + wave * 16 + p;
        float acc = 0.f;
#pragma unroll
        for (int k = 0; k < K_; k++) {
            float p0 = dcn[(k * 3 + 0) * N_ + i] * 4.f;
            float p1 = dcn[(k * 3 + 1) * N_ + i] * 4.f;
            float p2 = dcn[(k * 3 + 2) * N_ + i] * 4.f;
            float i0 = fminf(fmaxf(floorf(p0), 0.f), 3.f);
            float i1 = fminf(fmaxf(floorf(p1), 0.f), 3.f);
            float i2 = fminf(fmaxf(floorf(p2), 0.f), 3.f);
            float f0 = p0 - i0, f1 = p1 - i1, f2 = p2 - i2;
            float g0 = 1.f - f0, g1 = 1.f - f1, g2 = 1.f - f2;
            int base = (int)i0 + 5 * (int)i1 + 25 * (int)i2;
            const float* w0 = &ws[base * 64 + f];
            acc += (g0 * g1 * g2) * w0[0];
            acc += (f0 * g1 * g2) * w0[64];
            acc += (g0 * f1 * g2) * w0[5 * 64];
            acc += (f0 * f1 * g2) * w0[6 * 64];
            acc += (g0 * g1 * f2) * w0[25 * 64];
            acc += (f0 * g1 * f2) * w0[26 * 64];
            acc += (g0 * f1 * f2) * w0[30 * 64];
            acc += (f0 * f1 * f2) * w0[31 * 64];
        }
        float xv = acc * (1.f / 16.f) + wr;
        x[i * 64 + f] = xv;
        s1 += xv; s2 += xv * xv;
    }
    red[wave][f] = s1; __syncthreads();
    if (threadIdx.x < 64)
        partials[blockIdx.x * 128 + f] = red[0][f] + red[1][f] + red[2][f] + red[3][f];
    __syncthreads();
    red[wave][f] = s2; __syncthreads();
    if (threadIdx.x < 64)
        partials[blockIdx.x * 128 + 64 + f] = red[0][f] + red[1][f] + red[2][f] + red[3][f];
}

// ----------------------- Kernel 4: BN stats finalize -------------------------
__global__ __launch_bounds__(256) void stats_kernel(const float* __restrict__ partials,
                                                    const float* __restrict__ gamma,
                                                    const float* __restrict__ beta,
                                                    float* __restrict__ stats) {
    __shared__ double red1[256], red2[256];
    int t = threadIdx.x;
    int f = t & 63, g = t >> 6;
    double s1 = 0.0, s2 = 0.0;
    for (int b2 = g; b2 < 1024; b2 += 4) {
        s1 += (double)partials[b2 * 128 + f];
        s2 += (double)partials[b2 * 128 + 64 + f];
    }
    red1[t] = s1; red2[t] = s2;
    __syncthreads();
    if (t < 64) {
        double S1 = red1[t] + red1[t + 64] + red1[t + 128] + red1[t + 192];
        double S2 = red2[t] + red2[t + 64] + red2[t + 128] + red2[t + 192];
        double mu = S1 / (double)N_;
        double var = S2 / (double)N_ - mu * mu;
        double scale = (double)gamma[t] / sqrt(var + (double)EPS_);
        double shift = (double)beta[t] - mu * scale;
        stats[t] = (float)scale;
        stats[64 + t] = (float)shift;
    }
}

// -------------- Kernel 5a: sigmoid + per-batch-chunk partial pool ------------
__global__ __launch_bounds__(256) void pool_partial_kernel(const float* __restrict__ x,
                                                           const float* __restrict__ stats,
                                                           float* __restrict__ pp) {
    __shared__ float red[4][64];
    int blk = blockIdx.x;
    int b = blk >> 3, ch = blk & 7;
    int f = threadIdx.x & 63, w = threadIdx.x >> 6;
    float scale = stats[f], shift = stats[64 + f];
    float acc = 0.f;
    int row0 = b * P_ + ch * 256;
    for (int r = w; r < 256; r += 4) {
        float v = x[(row0 + r) * 64 + f];
        float t = v * scale + shift;
        acc += 1.f / (1.f + expf(-t));
    }
    red[w][f] = acc; __syncthreads();
    if (threadIdx.x < 64) pp[blk * 64 + f] = red[0][f] + red[1][f] + red[2][f] + red[3][f];
}

// ---------------------- Kernel 5b: finalize batch means ----------------------
__global__ void pool_final_kernel(const float* __restrict__ pp, float* __restrict__ ys) {
    for (int idx = threadIdx.x; idx < B_ * 64; idx += 256) {
        int b = idx >> 6, f = idx & 63;
        float s = 0.f;
#pragma unroll
        for (int g = 0; g < 8; g++) s += pp[(b * 8 + g) * 64 + f];
        ys[idx] = s * (1.f / 2048.f);
    }
}

// -------------------- Kernel 6: MLP + log_softmax (1 block) ------------------
__global__ __launch_bounds__(256) void mlp_kernel(const float* __restrict__ ys,
                                                  const float* __restrict__ w1,
                                                  const float* __restrict__ b1,
                                                  const float* __restrict__ w2,
                                                  const float* __restrict__ b2,
                                                  float* __restrict__ out) {
    __shared__ float sy[B_ * F_];
    __shared__ float sy1[B_ * H_];
    __shared__ float sy2[B_ * NC_];
    for (int t = threadIdx.x; t < B_ * F_; t += 256) sy[t] = ys[t];
    __syncthreads();
    for (int idx = threadIdx.x; idx < B_ * H_; idx += 256) {
        int b = idx >> 8, j = idx & 255;
        float acc = b1[j];
#pragma unroll 8
        for (int c = 0; c < F_; c++) acc += sy[b * 64 + c] * w1[c * 256 + j];
        sy1[idx] = acc > 0.f ? acc : expm1f(acc);
    }
    __syncthreads();
    for (int idx = threadIdx.x; idx < B_ * NC_; idx += 256) {
        int b = idx / NC_, j = idx % NC_;
        float acc = b2[j];
#pragma unroll 8
        for (int c = 0; c < H_; c++) acc += sy1[b * 256 + c] * w2[c * 40 + j];
        sy2[idx] = acc;
    }
    __syncthreads();
    if (threadIdx.x < B_) {
        int b = threadIdx.x;
        float m = -INFINITY;
        for (int j = 0; j < NC_; j++) m = fmaxf(m, sy2[b * NC_ + j]);
        float s = 0.f;
        for (int j = 0; j < NC_; j++) s += expf(sy2[b * NC_ + j] - m);
        float lse = logf(s);
        for (int j = 0; j < NC_; j++) out[b * NC_ + j] = sy2[b * NC_ + j] - m - lse;
    }
}

extern "C" void kernel_launch(void* const* d_in, const int* in_sizes, int n_in,
                              void* d_out, int out_size, void* d_ws, size_t ws_size,
                              hipStream_t stream) {
    const float* pos      = (const float*)d_in[0];
    const float* w_spline = (const float*)d_in[2];
    const float* w_root   = (const float*)d_in[3];
    const float* b_spline = (const float*)d_in[4];
    const float* bn_gamma = (const float*)d_in[5];
    const float* bn_beta  = (const float*)d_in[6];
    const float* w1       = (const float*)d_in[7];
    const float* b1       = (const float*)d_in[8];
    const float* w2       = (const float*)d_in[9];
    const float* b2       = (const float*)d_in[10];
    float* out = (float*)d_out;

    char* ws = (char*)d_ws;
    int*   nbr      = (int*)(ws + 0);                      // 4 MB
    float* dcn      = (float*)(ws + (4u << 20));           // 12 MB
    float* x        = (float*)(ws + (16u << 20));          // 16 MB
    float* partials = (float*)(ws + (32u << 20));          // 512 KB
    float* stats    = (float*)(ws + (32u << 20) + (512u << 10));        // 512 B
    float* pp       = (float*)(ws + (32u << 20) + (512u << 10) + 4096); // 64 KB
    float* ys       = (float*)(ws + (32u << 20) + (512u << 10) + 4096 + (64u << 10)); // 8 KB

    knn_kernel<<<B_ * 8, 1024, 0, stream>>>(pos, nbr);
    geom_kernel<<<N_ / 256, 256, 0, stream>>>(pos, nbr, dcn);
    spline_kernel<<<N_ / 64, 256, 0, stream>>>(dcn, w_spline, w_root, b_spline, x, partials);
    stats_kernel<<<1, 256, 0, stream>>>(partials, bn_gamma, bn_beta, stats);
    pool_partial_kernel<<<B_ * 8, 256, 0, stream>>>(x, stats, pp);
    pool_final_kernel<<<1, 256, 0, stream>>>(pp, ys);
    mlp_kernel<<<1, 256, 0, stream>>>(ys, w1, b1, w2, b2, out);
}

// Round 3
// 450.682 us; speedup vs baseline: 2.4931x; 1.1889x over previous
//
#include <hip/hip_runtime.h>
#include <math.h>

#define B_ 32
#define P_ 2048
#define N_ 65536
#define K_ 16
#define L_ 8
#define F_ 64
#define KS_ 5
#define KS3_ 125
#define NC_ 40
#define H_ 256
#define EPS_ 1e-5f

// exact same fp expression used in scan and merge (pinned fmaf order)
__device__ __forceinline__ float distf(float4 C, float nx, float ny, float nz, float qs) {
    return fmaf(C.x, nx, fmaf(C.y, ny, fmaf(C.z, nz, C.w))) + qs;
}

// static-index sorted insertion (stays in VGPRs)
__device__ __forceinline__ void insert16(float (&bd)[16], int (&bi)[16], float cd, int ci) {
#pragma unroll
    for (int m = 0; m < 16; m++) {
        bool sw = cd < bd[m];
        float td = sw ? bd[m] : cd;
        int   ti = sw ? bi[m] : ci;
        bd[m] = sw ? cd : bd[m];
        bi[m] = sw ? ci : bi[m];
        cd = td; ci = ti;
    }
}

// ---------------- Kernel 1: KNN (4 segments/query in-block + merge) ----------
__global__ __launch_bounds__(1024) void knn_kernel(const float* __restrict__ pos,
                                                   int* __restrict__ nbr) {
    __shared__ float4 cloud[P_];                 // 32 KB
    __shared__ unsigned short lists[1024 * 16];  // 32 KB, [seg][q][16]
    int b = blockIdx.x >> 3, tile = blockIdx.x & 7;
    int base = b * P_;
    int t = threadIdx.x;
    for (int j = t; j < P_; j += 1024) {
        float x = pos[(base + j) * 3 + 0];
        float y = pos[(base + j) * 3 + 1];
        float z = pos[(base + j) * 3 + 2];
        cloud[j] = make_float4(x, y, z, x * x + y * y + z * z);
    }
    __syncthreads();

    int seg = t >> 8, q = t & 255;
    int il = tile * 256 + q;
    float4 Q = cloud[il];
    float nx = -2.f * Q.x, ny = -2.f * Q.y, nz = -2.f * Q.z, qs = Q.w;

    float bd[16]; int bi[16];
#pragma unroll
    for (int m = 0; m < 16; m++) { bd[m] = INFINITY; bi[m] = 0; }
    // depth-4 lazy accept buffer (static-indexed shift register)
    float e0d = INFINITY, e1d = INFINITY, e2d = INFINITY, e3d = INFINITY;
    int   e0i = 0, e1i = 0, e2i = 0, e3i = 0;
    int cnt = 0;
    float thr = INFINITY;                        // stale-but-safe threshold

    int j0 = seg << 9;
    float4 C = cloud[j0];
    for (int jj = 0; jj < 512; jj++) {
        float4 Cn = cloud[j0 + ((jj + 1) & 511)];   // prefetch (wraps, harmless)
        int j = j0 + jj;
        float d = distf(C, nx, ny, nz, qs);
        bool acc = (d < thr) && (j != il);
        e3d = acc ? e2d : e3d;  e3i = acc ? e2i : e3i;
        e2d = acc ? e1d : e2d;  e2i = acc ? e1i : e2i;
        e1d = acc ? e0d : e1d;  e1i = acc ? e0i : e1i;
        e0d = acc ? d   : e0d;  e0i = acc ? j   : e0i;
        cnt += acc;
        if (__any(cnt >= 4)) {
            insert16(bd, bi, e3d, e3i);   // oldest first: ascending-j stability
            insert16(bd, bi, e2d, e2i);
            insert16(bd, bi, e1d, e1i);
            insert16(bd, bi, e0d, e0i);
            e0d = INFINITY; e1d = INFINITY; e2d = INFINITY; e3d = INFINITY;
            cnt = 0;
            thr = bd[15];
        }
        C = Cn;
    }
    insert16(bd, bi, e3d, e3i);
    insert16(bd, bi, e2d, e2i);
    insert16(bd, bi, e1d, e1i);
    insert16(bd, bi, e0d, e0i);

#pragma unroll
    for (int m = 0; m < 16; m++) lists[t * 16 + m] = (unsigned short)bi[m];
    __syncthreads();

    // merge: threads 0..255, one query each; recompute d bit-identically from LDS
    if (t < 256) {
        int il2 = tile * 256 + t;
        float4 Q2 = cloud[il2];
        float nx2 = -2.f * Q2.x, ny2 = -2.f * Q2.y, nz2 = -2.f * Q2.z, qs2 = Q2.w;
        float md[16]; int mi[16];
#pragma unroll
        for (int m = 0; m < 16; m++) { md[m] = INFINITY; mi[m] = 0; }
        for (int s = 0; s < 4; s++) {
#pragma unroll
            for (int r = 0; r < 16; r++) {
                int j = lists[((s << 8) | t) * 16 + r];
                float4 Cm = cloud[j];
                insert16(md, mi, distf(Cm, nx2, ny2, nz2, qs2), j);
            }
        }
#pragma unroll
        for (int m = 0; m < 16; m++) nbr[m * N_ + base + il2] = base + mi[m];
    }
}

// ------------- Kernel 2: cov + 5x QR (LAPACK Householder) + dc ---------------
// writes dcn in [N][48] layout (12 float4 per point)
__global__ __launch_bounds__(256) void geom_kernel(const float* __restrict__ pos,
                                                   const int* __restrict__ nbr,
                                                   float* __restrict__ dcn) {
    int i = blockIdx.x * 256 + threadIdx.x;
    float px = pos[i * 3 + 0], py = pos[i * 3 + 1], pz = pos[i * 3 + 2];
    float cx[K_], cy[K_], cz[K_];
#pragma unroll
    for (int k = 0; k < K_; k++) {
        int n = nbr[k * N_ + i];
        cx[k] = pos[n * 3 + 0] - px;
        cy[k] = pos[n * 3 + 1] - py;
        cz[k] = pos[n * 3 + 2] - pz;
    }
    float A[3][3];
    {
        float a00 = 0, a01 = 0, a02 = 0, a11 = 0, a12 = 0, a22 = 0;
#pragma unroll
        for (int l = 0; l < L_; l++) {
            a00 += cx[l] * cx[l]; a01 += cx[l] * cy[l]; a02 += cx[l] * cz[l];
            a11 += cy[l] * cy[l]; a12 += cy[l] * cz[l]; a22 += cz[l] * cz[l];
        }
        A[0][0] = a00; A[0][1] = a01; A[0][2] = a02;
        A[1][0] = a01; A[1][1] = a11; A[1][2] = a12;
        A[2][0] = a02; A[2][1] = a12; A[2][2] = a22;
    }
    float Vt[3][3] = {{1.f, 0.f, 0.f}, {0.f, 1.f, 0.f}, {0.f, 0.f, 1.f}};

    for (int it = 0; it < 5; it++) {
        float M00 = A[0][0], M01 = A[0][1], M02 = A[0][2];
        float M10 = A[1][0], M11 = A[1][1], M12 = A[1][2];
        float M20 = A[2][0], M21 = A[2][1], M22 = A[2][2];
        float tau0 = 0.f, v1 = 0.f, v2 = 0.f;
        float xn2 = M10 * M10 + M20 * M20;
        if (xn2 != 0.f) {
            float beta = -copysignf(sqrtf(M00 * M00 + xn2), M00);
            tau0 = (beta - M00) / beta;
            float inv = 1.f / (M00 - beta);
            v1 = M10 * inv; v2 = M20 * inv;
            float s;
            s = tau0 * (M01 + v1 * M11 + v2 * M21); M01 -= s; M11 -= v1 * s; M21 -= v2 * s;
            s = tau0 * (M02 + v1 * M12 + v2 * M22); M02 -= s; M12 -= v1 * s; M22 -= v2 * s;
            M00 = beta;
        }
        float tau1 = 0.f, u2 = 0.f;
        if (M21 != 0.f) {
            float beta1 = -copysignf(sqrtf(M11 * M11 + M21 * M21), M11);
            tau1 = (beta1 - M11) / beta1;
            u2 = M21 / (M11 - beta1);
            float s = tau1 * (M12 + u2 * M22); M12 -= s; M22 -= u2 * s;
            M11 = beta1;
        }
        float h11 = 1.f - tau1, h12 = -tau1 * u2, h22 = 1.f - tau1 * u2 * u2;
        float Q[3][3];
        Q[0][0] = 1.f - tau0;
        Q[1][0] = -v1 * tau0;
        Q[2][0] = -v2 * tau0;
        float t1 = tau0 * (v1 * h11 + v2 * h12);
        Q[0][1] = -t1;
        Q[1][1] = h11 - v1 * t1;
        Q[2][1] = h12 - v2 * t1;
        float t2 = tau0 * (v1 * h12 + v2 * h22);
        Q[0][2] = -t2;
        Q[1][2] = h12 - v1 * t2;
        Q[2][2] = h22 - v2 * t2;
        A[0][0] = M00 * Q[0][0] + M01 * Q[1][0] + M02 * Q[2][0];
        A[0][1] = M00 * Q[0][1] + M01 * Q[1][1] + M02 * Q[2][1];
        A[0][2] = M00 * Q[0][2] + M01 * Q[1][2] + M02 * Q[2][2];
        A[1][0] = M11 * Q[1][0] + M12 * Q[2][0];
        A[1][1] = M11 * Q[1][1] + M12 * Q[2][1];
        A[1][2] = M11 * Q[1][2] + M12 * Q[2][2];
        A[2][0] = M22 * Q[2][0];
        A[2][1] = M22 * Q[2][1];
        A[2][2] = M22 * Q[2][2];
        float nv[3][3];
#pragma unroll
        for (int r = 0; r < 3; r++)
#pragma unroll
            for (int c = 0; c < 3; c++)
                nv[r][c] = Vt[r][0] * Q[0][c] + Vt[r][1] * Q[1][c] + Vt[r][2] * Q[2][c];
#pragma unroll
        for (int r = 0; r < 3; r++)
#pragma unroll
            for (int c = 0; c < 3; c++) Vt[r][c] = nv[r][c];
    }

    float s2 = 0.f, mx01 = 0.f, mx2 = 0.f;
#pragma unroll
    for (int k = 0; k < K_; k++) {
        float d0 = cx[k] * Vt[0][0] + cy[k] * Vt[1][0] + cz[k] * Vt[2][0];
        float d1 = cx[k] * Vt[0][1] + cy[k] * Vt[1][1] + cz[k] * Vt[2][1];
        float d2 = cx[k] * Vt[0][2] + cy[k] * Vt[1][2] + cz[k] * Vt[2][2];
        s2 += d2;
        mx01 = fmaxf(mx01, fmaxf(fabsf(d0), fabsf(d1)));
        mx2  = fmaxf(mx2, fabsf(d2));
    }
    float sg = (s2 > 0.f) ? 1.f : ((s2 < 0.f) ? -1.f : 0.f);
    float mx = fmaxf(mx01, (sg == 0.f) ? 0.f : mx2);
    float hs = 0.5f / mx;
    float o[48];
#pragma unroll
    for (int k = 0; k < K_; k++) {
        float d0 = cx[k] * Vt[0][0] + cy[k] * Vt[1][0] + cz[k] * Vt[2][0];
        float d1 = cx[k] * Vt[0][1] + cy[k] * Vt[1][1] + cz[k] * Vt[2][1];
        float d2 = (cx[k] * Vt[0][2] + cy[k] * Vt[1][2] + cz[k] * Vt[2][2]) * sg;
        o[k * 3 + 0] = d0 * hs + 0.5f;
        o[k * 3 + 1] = d1 * hs + 0.5f;
        o[k * 3 + 2] = d2 * hs + 0.5f;
    }
    float4* row = (float4*)(dcn + (size_t)i * 48);
#pragma unroll
    for (int m = 0; m < 12; m++)
        row[m] = make_float4(o[m * 4 + 0], o[m * 4 + 1], o[m * 4 + 2], o[m * 4 + 3]);
}

// ---------- Kernel 3: trilinear spline gather + out_nondir + BN partials -----
// LDS table transposed: ws_t[f*125 + cell] -> per-k reads are 4x ds_read2_b32
// off one vaddr (offsets 0/1, 5/6, 25/26, 30/31). Bank index = 29*f + c (mod 32),
// gcd(29,32)=1 -> exactly 2-way aliasing = conflict-free.
__global__ __launch_bounds__(256) void spline_kernel(const float* __restrict__ dcn,
                                                     const float* __restrict__ w_spline,
                                                     const float* __restrict__ w_root,
                                                     const float* __restrict__ b_spline,
                                                     float* __restrict__ x,
                                                     float* __restrict__ partials) {
    __shared__ float ws_t[F_ * KS3_];   // [f][cell], 32000 B
    __shared__ float red[4][64];
    {
        int f = threadIdx.x & 63;
        for (int c = threadIdx.x >> 6; c < KS3_; c += 4)
            ws_t[f * KS3_ + c] = w_spline[c * 64 + f];
    }
    __syncthreads();
    int wave = threadIdx.x >> 6, f = threadIdx.x & 63;
    const float* wbase = &ws_t[f * KS3_];
    float wr = w_root[f] + b_spline[f];
    float s1 = 0.f, s2 = 0.f;
    for (int p = 0; p < 16; p++) {
        int i = blockIdx.x * 64 + wave * 16 + p;
        const float4* row = (const float4*)(dcn + (size_t)i * 48);
        float pr[48];
#pragma unroll
        for (int m = 0; m < 12; m++) {
            float4 v = row[m];
            pr[m * 4 + 0] = v.x; pr[m * 4 + 1] = v.y;
            pr[m * 4 + 2] = v.z; pr[m * 4 + 3] = v.w;
        }
        float acc = 0.f;
#pragma unroll
        for (int k = 0; k < K_; k++) {
            float p0 = pr[k * 3 + 0] * 4.f;
            float p1 = pr[k * 3 + 1] * 4.f;
            float p2 = pr[k * 3 + 2] * 4.f;
            float i0 = fminf(fmaxf(floorf(p0), 0.f), 3.f);
            float i1 = fminf(fmaxf(floorf(p1), 0.f), 3.f);
            float i2 = fminf(fmaxf(floorf(p2), 0.f), 3.f);
            float f0 = p0 - i0, f1 = p1 - i1, f2 = p2 - i2;
            float g0 = 1.f - f0, g1 = 1.f - f1, g2 = 1.f - f2;
            int c = (int)i0 + 5 * (int)i1 + 25 * (int)i2;
            const float* wp = wbase + c;
            float a0 = wp[0],  a1 = wp[1];    // (i0,i1,i2), (i0+1,i1,i2)
            float b0 = wp[5],  b1v = wp[6];   // i1+1
            float c0 = wp[25], c1 = wp[26];   // i2+1
            float d0 = wp[30], d1 = wp[31];   // i1+1, i2+1
            float wA = g1 * g2, wB = f1 * g2, wC = g1 * f2, wD = f1 * f2;
            acc = fmaf(wA, fmaf(f0, a1, g0 * a0), acc);
            acc = fmaf(wB, fmaf(f0, b1v, g0 * b0), acc);
            acc = fmaf(wC, fmaf(f0, c1, g0 * c0), acc);
            acc = fmaf(wD, fmaf(f0, d1, g0 * d0), acc);
        }
        float xv = acc * (1.f / 16.f) + wr;
        x[(size_t)i * 64 + f] = xv;
        s1 += xv; s2 += xv * xv;
    }
    red[wave][f] = s1; __syncthreads();
    if (threadIdx.x < 64)
        partials[blockIdx.x * 128 + f] = red[0][f] + red[1][f] + red[2][f] + red[3][f];
    __syncthreads();
    red[wave][f] = s2; __syncthreads();
    if (threadIdx.x < 64)
        partials[blockIdx.x * 128 + 64 + f] = red[0][f] + red[1][f] + red[2][f] + red[3][f];
}

// ----------------------- Kernel 4: BN stats finalize -------------------------
__global__ __launch_bounds__(256) void stats_kernel(const float* __restrict__ partials,
                                                    const float* __restrict__ gamma,
                                                    const float* __restrict__ beta,
                                                    float* __restrict__ stats) {
    __shared__ double red1[256], red2[256];
    int t = threadIdx.x;
    int f = t & 63, g = t >> 6;
    double s1 = 0.0, s2 = 0.0;
    for (int b2 = g; b2 < 1024; b2 += 4) {
        s1 += (double)partials[b2 * 128 + f];
        s2 += (double)partials[b2 * 128 + 64 + f];
    }
    red1[t] = s1; red2[t] = s2;
    __syncthreads();
    if (t < 64) {
        double S1 = red1[t] + red1[t + 64] + red1[t + 128] + red1[t + 192];
        double S2 = red2[t] + red2[t + 64] + red2[t + 128] + red2[t + 192];
        double mu = S1 / (double)N_;
        double var = S2 / (double)N_ - mu * mu;
        double scale = (double)gamma[t] / sqrt(var + (double)EPS_);
        double shift = (double)beta[t] - mu * scale;
        stats[t] = (float)scale;
        stats[64 + t] = (float)shift;
    }
}

// -------------- Kernel 5a: sigmoid + per-batch-chunk partial pool ------------
__global__ __launch_bounds__(256) void pool_partial_kernel(const float* __restrict__ x,
                                                           const float* __restrict__ stats,
                                                           float* __restrict__ pp) {
    __shared__ float red[4][64];
    int blk = blockIdx.x;
    int b = blk >> 3, ch = blk & 7;
    int f = threadIdx.x & 63, w = threadIdx.x >> 6;
    float scale = stats[f], shift = stats[64 + f];
    float acc = 0.f;
    int row0 = b * P_ + ch * 256;
    for (int r = w; r < 256; r += 4) {
        float v = x[(size_t)(row0 + r) * 64 + f];
        float t = v * scale + shift;
        acc += 1.f / (1.f + expf(-t));
    }
    red[w][f] = acc; __syncthreads();
    if (threadIdx.x < 64) pp[blk * 64 + f] = red[0][f] + red[1][f] + red[2][f] + red[3][f];
}

// ---------------------- Kernel 5b: finalize batch means ----------------------
__global__ void pool_final_kernel(const float* __restrict__ pp, float* __restrict__ ys) {
    for (int idx = threadIdx.x; idx < B_ * 64; idx += 256) {
        int b = idx >> 6, f = idx & 63;
        float s = 0.f;
#pragma unroll
        for (int g = 0; g < 8; g++) s += pp[(b * 8 + g) * 64 + f];
        ys[idx] = s * (1.f / 2048.f);
    }
}

// -------------------- Kernel 6: MLP + log_softmax (1 block) ------------------
__global__ __launch_bounds__(256) void mlp_kernel(const float* __restrict__ ys,
                                                  const float* __restrict__ w1,
                                                  const float* __restrict__ b1,
                                                  const float* __restrict__ w2,
                                                  const float* __restrict__ b2,
                                                  float* __restrict__ out) {
    __shared__ float sy[B_ * F_];
    __shared__ float sy1[B_ * H_];
    __shared__ float sy2[B_ * NC_];
    for (int t = threadIdx.x; t < B_ * F_; t += 256) sy[t] = ys[t];
    __syncthreads();
    for (int idx = threadIdx.x; idx < B_ * H_; idx += 256) {
        int b = idx >> 8, j = idx & 255;
        float acc = b1[j];
#pragma unroll 8
        for (int c = 0; c < F_; c++) acc += sy[b * 64 + c] * w1[c * 256 + j];
        sy1[idx] = acc > 0.f ? acc : expm1f(acc);
    }
    __syncthreads();
    for (int idx = threadIdx.x; idx < B_ * NC_; idx += 256) {
        int b = idx / NC_, j = idx % NC_;
        float acc = b2[j];
#pragma unroll 8
        for (int c = 0; c < H_; c++) acc += sy1[b * 256 + c] * w2[c * 40 + j];
        sy2[idx] = acc;
    }
    __syncthreads();
    if (threadIdx.x < B_) {
        int b = threadIdx.x;
        float m = -INFINITY;
        for (int j = 0; j < NC_; j++) m = fmaxf(m, sy2[b * NC_ + j]);
        float s = 0.f;
        for (int j = 0; j < NC_; j++) s += expf(sy2[b * NC_ + j] - m);
        float lse = logf(s);
        for (int j = 0; j < NC_; j++) out[b * NC_ + j] = sy2[b * NC_ + j] - m - lse;
    }
}

extern "C" void kernel_launch(void* const* d_in, const int* in_sizes, int n_in,
                              void* d_out, int out_size, void* d_ws, size_t ws_size,
                              hipStream_t stream) {
    const float* pos      = (const float*)d_in[0];
    const float* w_spline = (const float*)d_in[2];
    const float* w_root   = (const float*)d_in[3];
    const float* b_spline = (const float*)d_in[4];
    const float* bn_gamma = (const float*)d_in[5];
    const float* bn_beta  = (const float*)d_in[6];
    const float* w1       = (const float*)d_in[7];
    const float* b1       = (const float*)d_in[8];
    const float* w2       = (const float*)d_in[9];
    const float* b2       = (const float*)d_in[10];
    float* out = (float*)d_out;

    char* ws = (char*)d_ws;
    int*   nbr      = (int*)(ws + 0);                      // 4 MB
    float* dcn      = (float*)(ws + (4u << 20));           // 12 MB
    float* x        = (float*)(ws + (16u << 20));          // 16 MB
    float* partials = (float*)(ws + (32u << 20));          // 512 KB
    float* stats    = (float*)(ws + (32u << 20) + (512u << 10));        // 512 B
    float* pp       = (float*)(ws + (32u << 20) + (512u << 10) + 4096); // 64 KB
    float* ys       = (float*)(ws + (32u << 20) + (512u << 10) + 4096 + (64u << 10)); // 8 KB

    knn_kernel<<<B_ * 8, 1024, 0, stream>>>(pos, nbr);
    geom_kernel<<<N_ / 256, 256, 0, stream>>>(pos, nbr, dcn);
    spline_kernel<<<N_ / 64, 256, 0, stream>>>(dcn, w_spline, w_root, b_spline, x, partials);
    stats_kernel<<<1, 256, 0, stream>>>(partials, bn_gamma, bn_beta, stats);
    pool_partial_kernel<<<B_ * 8, 256, 0, stream>>>(x, stats, pp);
    pool_final_kernel<<<1, 256, 0, stream>>>(pp, ys);
    mlp_kernel<<<1, 256, 0, stream>>>(ys, w1, b1, w2, b2, out);
}

// Round 4
// 382.804 us; speedup vs baseline: 2.9351x; 1.1773x over previous
//
#include <hip/hip_runtime.h>
#include <math.h>

#define B_ 32
#define P_ 2048
#define N_ 65536
#define K_ 16
#define L_ 8
#define F_ 64
#define KS_ 5
#define KS3_ 125
#define NC_ 40
#define H_ 256
#define EPS_ 1e-5f

// exact same fp expression used in scan and merge (pinned fmaf order)
__device__ __forceinline__ float distf(float4 C, float nx, float ny, float nz, float qs) {
    return fmaf(C.x, nx, fmaf(C.y, ny, fmaf(C.z, nz, C.w))) + qs;
}

// packed-key insertion: pure min/max chain, 2 inst per slot
__device__ __forceinline__ void insU(unsigned (&bu)[16], unsigned k) {
#pragma unroll
    for (int m = 0; m < 16; m++) {
        unsigned mn = min(bu[m], k);
        k = max(bu[m], k);
        bu[m] = mn;
    }
}

// exact (float,int) sorted insertion for the merge phase
__device__ __forceinline__ void insert16(float (&bd)[16], int (&bi)[16], float cd, int ci) {
#pragma unroll
    for (int m = 0; m < 16; m++) {
        bool sw = cd < bd[m];
        float td = sw ? bd[m] : cd;
        int   ti = sw ? bi[m] : ci;
        bd[m] = sw ? cd : bd[m];
        bi[m] = sw ? ci : bi[m];
        cd = td; ci = ti;
    }
}

// ---------------- Kernel 1: KNN (4 segments/query in-block + merge) ----------
// Scan phase selects per-segment top-16 by packed key (21-bit dist prefix |
// 11-bit index): selection-only approximation; merge phase recomputes exact
// f32 distances and does the exact stable (d, j) ordering.
__global__ __launch_bounds__(1024) void knn_kernel(const float* __restrict__ pos,
                                                   int* __restrict__ nbr) {
    __shared__ float4 cloud[P_];                 // 32 KB
    __shared__ unsigned short lists[1024 * 16];  // 32 KB, [seg][q][16]
    int b = blockIdx.x >> 3, tile = blockIdx.x & 7;
    int base = b * P_;
    int t = threadIdx.x;
    for (int j = t; j < P_; j += 1024) {
        float x = pos[(base + j) * 3 + 0];
        float y = pos[(base + j) * 3 + 1];
        float z = pos[(base + j) * 3 + 2];
        cloud[j] = make_float4(x, y, z, x * x + y * y + z * z);
    }
    __syncthreads();

    int seg = t >> 8, q = t & 255;
    int il = tile * 256 + q;
    float4 Q = cloud[il];
    float nx = -2.f * Q.x, ny = -2.f * Q.y, nz = -2.f * Q.z, qs = Q.w;

    unsigned bu[16];
#pragma unroll
    for (int m = 0; m < 16; m++) bu[m] = 0xFFFFFFFFu;
    // depth-6 lazy accept buffer of packed keys (static-indexed shift register)
    unsigned e0 = ~0u, e1 = ~0u, e2 = ~0u, e3 = ~0u, e4 = ~0u, e5 = ~0u;
    int cnt = 0;
    unsigned thr = 0xFFFFFFFFu;                  // stale-but-safe packed threshold

    int j0 = seg << 9;
    float4 C = cloud[j0];
    for (int jj = 0; jj < 512; jj++) {
        float4 Cn = cloud[j0 + ((jj + 1) & 511)];   // prefetch (wraps, harmless)
        int j = j0 + jj;
        float d = distf(C, nx, ny, nz, qs);
        unsigned key = (__float_as_uint(fmaxf(d, 0.f)) & 0xFFFFF800u) | (unsigned)j;
        bool acc = (key < thr) && (j != il);
        e5 = acc ? e4 : e5;
        e4 = acc ? e3 : e4;
        e3 = acc ? e2 : e3;
        e2 = acc ? e1 : e2;
        e1 = acc ? e0 : e1;
        e0 = acc ? key : e0;
        cnt += acc;
        if (__any(cnt >= 6)) {
            insU(bu, e5); insU(bu, e4); insU(bu, e3);
            insU(bu, e2); insU(bu, e1); insU(bu, e0);
            e0 = e1 = e2 = e3 = e4 = e5 = 0xFFFFFFFFu;
            cnt = 0;
            thr = bu[15];
        }
        C = Cn;
    }
    insU(bu, e5); insU(bu, e4); insU(bu, e3);
    insU(bu, e2); insU(bu, e1); insU(bu, e0);

#pragma unroll
    for (int m = 0; m < 16; m++) lists[t * 16 + m] = (unsigned short)(bu[m] & 0x7FFu);
    __syncthreads();

    // merge: threads 0..255, one query each; recompute exact d from LDS
    if (t < 256) {
        int il2 = tile * 256 + t;
        float4 Q2 = cloud[il2];
        float nx2 = -2.f * Q2.x, ny2 = -2.f * Q2.y, nz2 = -2.f * Q2.z, qs2 = Q2.w;
        float md[16]; int mi[16];
#pragma unroll
        for (int m = 0; m < 16; m++) { md[m] = INFINITY; mi[m] = 0; }
        for (int s = 0; s < 4; s++) {
#pragma unroll
            for (int r = 0; r < 16; r++) {
                int j = lists[((s << 8) | t) * 16 + r];
                float4 Cm = cloud[j];
                insert16(md, mi, distf(Cm, nx2, ny2, nz2, qs2), j);
            }
        }
#pragma unroll
        for (int m = 0; m < 16; m++) nbr[m * N_ + base + il2] = base + mi[m];
    }
}

// ------------- Kernel 2: cov + 5x QR (LAPACK Householder) + dc ---------------
// writes dcn in [N][48] layout (12 float4 per point)
__global__ __launch_bounds__(256) void geom_kernel(const float* __restrict__ pos,
                                                   const int* __restrict__ nbr,
                                                   float* __restrict__ dcn) {
    int i = blockIdx.x * 256 + threadIdx.x;
    float px = pos[i * 3 + 0], py = pos[i * 3 + 1], pz = pos[i * 3 + 2];
    float cx[K_], cy[K_], cz[K_];
#pragma unroll
    for (int k = 0; k < K_; k++) {
        int n = nbr[k * N_ + i];
        cx[k] = pos[n * 3 + 0] - px;
        cy[k] = pos[n * 3 + 1] - py;
        cz[k] = pos[n * 3 + 2] - pz;
    }
    float A[3][3];
    {
        float a00 = 0, a01 = 0, a02 = 0, a11 = 0, a12 = 0, a22 = 0;
#pragma unroll
        for (int l = 0; l < L_; l++) {
            a00 += cx[l] * cx[l]; a01 += cx[l] * cy[l]; a02 += cx[l] * cz[l];
            a11 += cy[l] * cy[l]; a12 += cy[l] * cz[l]; a22 += cz[l] * cz[l];
        }
        A[0][0] = a00; A[0][1] = a01; A[0][2] = a02;
        A[1][0] = a01; A[1][1] = a11; A[1][2] = a12;
        A[2][0] = a02; A[2][1] = a12; A[2][2] = a22;
    }
    float Vt[3][3] = {{1.f, 0.f, 0.f}, {0.f, 1.f, 0.f}, {0.f, 0.f, 1.f}};

    for (int it = 0; it < 5; it++) {
        float M00 = A[0][0], M01 = A[0][1], M02 = A[0][2];
        float M10 = A[1][0], M11 = A[1][1], M12 = A[1][2];
        float M20 = A[2][0], M21 = A[2][1], M22 = A[2][2];
        float tau0 = 0.f, v1 = 0.f, v2 = 0.f;
        float xn2 = M10 * M10 + M20 * M20;
        if (xn2 != 0.f) {
            float beta = -copysignf(sqrtf(M00 * M00 + xn2), M00);
            tau0 = (beta - M00) / beta;
            float inv = 1.f / (M00 - beta);
            v1 = M10 * inv; v2 = M20 * inv;
            float s;
            s = tau0 * (M01 + v1 * M11 + v2 * M21); M01 -= s; M11 -= v1 * s; M21 -= v2 * s;
            s = tau0 * (M02 + v1 * M12 + v2 * M22); M02 -= s; M12 -= v1 * s; M22 -= v2 * s;
            M00 = beta;
        }
        float tau1 = 0.f, u2 = 0.f;
        if (M21 != 0.f) {
            float beta1 = -copysignf(sqrtf(M11 * M11 + M21 * M21), M11);
            tau1 = (beta1 - M11) / beta1;
            u2 = M21 / (M11 - beta1);
            float s = tau1 * (M12 + u2 * M22); M12 -= s; M22 -= u2 * s;
            M11 = beta1;
        }
        float h11 = 1.f - tau1, h12 = -tau1 * u2, h22 = 1.f - tau1 * u2 * u2;
        float Q[3][3];
        Q[0][0] = 1.f - tau0;
        Q[1][0] = -v1 * tau0;
        Q[2][0] = -v2 * tau0;
        float t1 = tau0 * (v1 * h11 + v2 * h12);
        Q[0][1] = -t1;
        Q[1][1] = h11 - v1 * t1;
        Q[2][1] = h12 - v2 * t1;
        float t2 = tau0 * (v1 * h12 + v2 * h22);
        Q[0][2] = -t2;
        Q[1][2] = h12 - v1 * t2;
        Q[2][2] = h22 - v2 * t2;
        A[0][0] = M00 * Q[0][0] + M01 * Q[1][0] + M02 * Q[2][0];
        A[0][1] = M00 * Q[0][1] + M01 * Q[1][1] + M02 * Q[2][1];
        A[0][2] = M00 * Q[0][2] + M01 * Q[1][2] + M02 * Q[2][2];
        A[1][0] = M11 * Q[1][0] + M12 * Q[2][0];
        A[1][1] = M11 * Q[1][1] + M12 * Q[2][1];
        A[1][2] = M11 * Q[1][2] + M12 * Q[2][2];
        A[2][0] = M22 * Q[2][0];
        A[2][1] = M22 * Q[2][1];
        A[2][2] = M22 * Q[2][2];
        float nv[3][3];
#pragma unroll
        for (int r = 0; r < 3; r++)
#pragma unroll
            for (int c = 0; c < 3; c++)
                nv[r][c] = Vt[r][0] * Q[0][c] + Vt[r][1] * Q[1][c] + Vt[r][2] * Q[2][c];
#pragma unroll
        for (int r = 0; r < 3; r++)
#pragma unroll
            for (int c = 0; c < 3; c++) Vt[r][c] = nv[r][c];
    }

    float s2 = 0.f, mx01 = 0.f, mx2 = 0.f;
#pragma unroll
    for (int k = 0; k < K_; k++) {
        float d0 = cx[k] * Vt[0][0] + cy[k] * Vt[1][0] + cz[k] * Vt[2][0];
        float d1 = cx[k] * Vt[0][1] + cy[k] * Vt[1][1] + cz[k] * Vt[2][1];
        float d2 = cx[k] * Vt[0][2] + cy[k] * Vt[1][2] + cz[k] * Vt[2][2];
        s2 += d2;
        mx01 = fmaxf(mx01, fmaxf(fabsf(d0), fabsf(d1)));
        mx2  = fmaxf(mx2, fabsf(d2));
    }
    float sg = (s2 > 0.f) ? 1.f : ((s2 < 0.f) ? -1.f : 0.f);
    float mx = fmaxf(mx01, (sg == 0.f) ? 0.f : mx2);
    float hs = 0.5f / mx;
    float o[48];
#pragma unroll
    for (int k = 0; k < K_; k++) {
        float d0 = cx[k] * Vt[0][0] + cy[k] * Vt[1][0] + cz[k] * Vt[2][0];
        float d1 = cx[k] * Vt[0][1] + cy[k] * Vt[1][1] + cz[k] * Vt[2][1];
        float d2 = (cx[k] * Vt[0][2] + cy[k] * Vt[1][2] + cz[k] * Vt[2][2]) * sg;
        o[k * 3 + 0] = d0 * hs + 0.5f;
        o[k * 3 + 1] = d1 * hs + 0.5f;
        o[k * 3 + 2] = d2 * hs + 0.5f;
    }
    float4* row = (float4*)(dcn + (size_t)i * 48);
#pragma unroll
    for (int m = 0; m < 12; m++)
        row[m] = make_float4(o[m * 4 + 0], o[m * 4 + 1], o[m * 4 + 2], o[m * 4 + 3]);
}

// ---------- Kernel 3: trilinear spline gather + out_nondir + BN partials -----
__global__ __launch_bounds__(256) void spline_kernel(const float* __restrict__ dcn,
                                                     const float* __restrict__ w_spline,
                                                     const float* __restrict__ w_root,
                                                     const float* __restrict__ b_spline,
                                                     float* __restrict__ x,
                                                     float* __restrict__ partials) {
    __shared__ float ws_t[F_ * KS3_];   // [f][cell], 32000 B
    __shared__ float red[4][64];
    {
        int f = threadIdx.x & 63;
        for (int c = threadIdx.x >> 6; c < KS3_; c += 4)
            ws_t[f * KS3_ + c] = w_spline[c * 64 + f];
    }
    __syncthreads();
    int wave = threadIdx.x >> 6, f = threadIdx.x & 63;
    const float* wbase = &ws_t[f * KS3_];
    float wr = w_root[f] + b_spline[f];
    float s1 = 0.f, s2 = 0.f;
    for (int p = 0; p < 16; p++) {
        int i = blockIdx.x * 64 + wave * 16 + p;
        const float4* row = (const float4*)(dcn + (size_t)i * 48);
        float pr[48];
#pragma unroll
        for (int m = 0; m < 12; m++) {
            float4 v = row[m];
            pr[m * 4 + 0] = v.x; pr[m * 4 + 1] = v.y;
            pr[m * 4 + 2] = v.z; pr[m * 4 + 3] = v.w;
        }
        float acc = 0.f;
#pragma unroll
        for (int k = 0; k < K_; k++) {
            float p0 = pr[k * 3 + 0] * 4.f;
            float p1 = pr[k * 3 + 1] * 4.f;
            float p2 = pr[k * 3 + 2] * 4.f;
            float i0 = fminf(fmaxf(floorf(p0), 0.f), 3.f);
            float i1 = fminf(fmaxf(floorf(p1), 0.f), 3.f);
            float i2 = fminf(fmaxf(floorf(p2), 0.f), 3.f);
            float f0 = p0 - i0, f1 = p1 - i1, f2 = p2 - i2;
            float g0 = 1.f - f0, g1 = 1.f - f1, g2 = 1.f - f2;
            int c = (int)i0 + 5 * (int)i1 + 25 * (int)i2;
            const float* wp = wbase + c;
            float a0 = wp[0],  a1 = wp[1];
            float b0 = wp[5],  b1v = wp[6];
            float c0 = wp[25], c1 = wp[26];
            float d0 = wp[30], d1 = wp[31];
            float wA = g1 * g2, wB = f1 * g2, wC = g1 * f2, wD = f1 * f2;
            acc = fmaf(wA, fmaf(f0, a1, g0 * a0), acc);
            acc = fmaf(wB, fmaf(f0, b1v, g0 * b0), acc);
            acc = fmaf(wC, fmaf(f0, c1, g0 * c0), acc);
            acc = fmaf(wD, fmaf(f0, d1, g0 * d0), acc);
        }
        float xv = acc * (1.f / 16.f) + wr;
        x[(size_t)i * 64 + f] = xv;
        s1 += xv; s2 += xv * xv;
    }
    red[wave][f] = s1; __syncthreads();
    if (threadIdx.x < 64)
        partials[blockIdx.x * 128 + f] = red[0][f] + red[1][f] + red[2][f] + red[3][f];
    __syncthreads();
    red[wave][f] = s2; __syncthreads();
    if (threadIdx.x < 64)
        partials[blockIdx.x * 128 + 64 + f] = red[0][f] + red[1][f] + red[2][f] + red[3][f];
}

// ----------------------- Kernel 4: BN stats finalize -------------------------
__global__ __launch_bounds__(256) void stats_kernel(const float* __restrict__ partials,
                                                    const float* __restrict__ gamma,
                                                    const float* __restrict__ beta,
                                                    float* __restrict__ stats) {
    __shared__ double red1[256], red2[256];
    int t = threadIdx.x;
    int f = t & 63, g = t >> 6;
    double s1 = 0.0, s2 = 0.0;
    for (int b2 = g; b2 < 1024; b2 += 4) {
        s1 += (double)partials[b2 * 128 + f];
        s2 += (double)partials[b2 * 128 + 64 + f];
    }
    red1[t] = s1; red2[t] = s2;
    __syncthreads();
    if (t < 64) {
        double S1 = red1[t] + red1[t + 64] + red1[t + 128] + red1[t + 192];
        double S2 = red2[t] + red2[t + 64] + red2[t + 128] + red2[t + 192];
        double mu = S1 / (double)N_;
        double var = S2 / (double)N_ - mu * mu;
        double scale = (double)gamma[t] / sqrt(var + (double)EPS_);
        double shift = (double)beta[t] - mu * scale;
        stats[t] = (float)scale;
        stats[64 + t] = (float)shift;
    }
}

// -------------- Kernel 5: sigmoid + per-batch-chunk partial pool -------------
__global__ __launch_bounds__(256) void pool_partial_kernel(const float* __restrict__ x,
                                                           const float* __restrict__ stats,
                                                           float* __restrict__ pp) {
    __shared__ float red[4][64];
    int blk = blockIdx.x;
    int b = blk >> 3, ch = blk & 7;
    int f = threadIdx.x & 63, w = threadIdx.x >> 6;
    float scale = stats[f], shift = stats[64 + f];
    float acc = 0.f;
    int row0 = b * P_ + ch * 256;
    for (int r = w; r < 256; r += 4) {
        float v = x[(size_t)(row0 + r) * 64 + f];
        float t = v * scale + shift;
        acc += 1.f / (1.f + expf(-t));
    }
    red[w][f] = acc; __syncthreads();
    if (threadIdx.x < 64) pp[blk * 64 + f] = red[0][f] + red[1][f] + red[2][f] + red[3][f];
}

// --------- Kernel 6: batch means + MLP + log_softmax (1 block, fused) --------
__global__ __launch_bounds__(256) void tail_kernel(const float* __restrict__ pp,
                                                   const float* __restrict__ w1,
                                                   const float* __restrict__ b1,
                                                   const float* __restrict__ w2,
                                                   const float* __restrict__ b2,
                                                   float* __restrict__ out) {
    __shared__ float sy[B_ * F_];
    __shared__ float sy1[B_ * H_];
    __shared__ float sy2[B_ * NC_];
    for (int idx = threadIdx.x; idx < B_ * F_; idx += 256) {
        int b = idx >> 6, f = idx & 63;
        float s = 0.f;
#pragma unroll
        for (int g = 0; g < 8; g++) s += pp[(b * 8 + g) * 64 + f];
        sy[idx] = s * (1.f / 2048.f);
    }
    __syncthreads();
    for (int idx = threadIdx.x; idx < B_ * H_; idx += 256) {
        int b = idx >> 8, j = idx & 255;
        float acc = b1[j];
#pragma unroll 8
        for (int c = 0; c < F_; c++) acc += sy[b * 64 + c] * w1[c * 256 + j];
        sy1[idx] = acc > 0.f ? acc : expm1f(acc);
    }
    __syncthreads();
    for (int idx = threadIdx.x; idx < B_ * NC_; idx += 256) {
        int b = idx / NC_, j = idx % NC_;
        float acc = b2[j];
#pragma unroll 8
        for (int c = 0; c < H_; c++) acc += sy1[b * 256 + c] * w2[c * 40 + j];
        sy2[idx] = acc;
    }
    __syncthreads();
    if (threadIdx.x < B_) {
        int b = threadIdx.x;
        float m = -INFINITY;
        for (int j = 0; j < NC_; j++) m = fmaxf(m, sy2[b * NC_ + j]);
        float s = 0.f;
        for (int j = 0; j < NC_; j++) s += expf(sy2[b * NC_ + j] - m);
        float lse = logf(s);
        for (int j = 0; j < NC_; j++) out[b * NC_ + j] = sy2[b * NC_ + j] - m - lse;
    }
}

extern "C" void kernel_launch(void* const* d_in, const int* in_sizes, int n_in,
                              void* d_out, int out_size, void* d_ws, size_t ws_size,
                              hipStream_t stream) {
    const float* pos      = (const float*)d_in[0];
    const float* w_spline = (const float*)d_in[2];
    const float* w_root   = (const float*)d_in[3];
    const float* b_spline = (const float*)d_in[4];
    const float* bn_gamma = (const float*)d_in[5];
    const float* bn_beta  = (const float*)d_in[6];
    const float* w1       = (const float*)d_in[7];
    const float* b1       = (const float*)d_in[8];
    const float* w2       = (const float*)d_in[9];
    const float* b2       = (const float*)d_in[10];
    float* out = (float*)d_out;

    char* ws = (char*)d_ws;
    int*   nbr      = (int*)(ws + 0);                      // 4 MB
    float* dcn      = (float*)(ws + (4u << 20));           // 12 MB
    float* x        = (float*)(ws + (16u << 20));          // 16 MB
    float* partials = (float*)(ws + (32u << 20));          // 512 KB
    float* stats    = (float*)(ws + (32u << 20) + (512u << 10));        // 512 B
    float* pp       = (float*)(ws + (32u << 20) + (512u << 10) + 4096); // 64 KB

    knn_kernel<<<B_ * 8, 1024, 0, stream>>>(pos, nbr);
    geom_kernel<<<N_ / 256, 256, 0, stream>>>(pos, nbr, dcn);
    spline_kernel<<<N_ / 64, 256, 0, stream>>>(dcn, w_spline, w_root, b_spline, x, partials);
    stats_kernel<<<1, 256, 0, stream>>>(partials, bn_gamma, bn_beta, stats);
    pool_partial_kernel<<<B_ * 8, 256, 0, stream>>>(x, stats, pp);
    tail_kernel<<<1, 256, 0, stream>>>(pp, w1, b1, w2, b2, out);
}

// Round 5
// 374.845 us; speedup vs baseline: 2.9974x; 1.0212x over previous
//
#include <hip/hip_runtime.h>
#include <math.h>

#define B_ 32
#define P_ 2048
#define N_ 65536
#define K_ 16
#define L_ 8
#define F_ 64
#define KS_ 5
#define KS3_ 125
#define NC_ 40
#define H_ 256
#define EPS_ 1e-5f

// exact same fp expression used in scan and merge (pinned fmaf order)
__device__ __forceinline__ float distf(float4 C, float nx, float ny, float nz, float qs) {
    return fmaf(C.x, nx, fmaf(C.y, ny, fmaf(C.z, nz, C.w))) + qs;
}

// packed-key insertion: pure min/max chain, 2 inst per slot
__device__ __forceinline__ void insU(unsigned (&bu)[16], unsigned k) {
#pragma unroll
    for (int m = 0; m < 16; m++) {
        unsigned mn = min(bu[m], k);
        k = max(bu[m], k);
        bu[m] = mn;
    }
}

// exact (float,int) sorted insertion for the merge phase
__device__ __forceinline__ void insert16(float (&bd)[16], int (&bi)[16], float cd, int ci) {
#pragma unroll
    for (int m = 0; m < 16; m++) {
        bool sw = cd < bd[m];
        float td = sw ? bd[m] : cd;
        int   ti = sw ? bi[m] : ci;
        bd[m] = sw ? cd : bd[m];
        bi[m] = sw ? ci : bi[m];
        cd = td; ci = ti;
    }
}

// ------- Kernel 1: KNN (4 segments/query) + merge + cov/QR/dc (fused) --------
// Scan selects per-segment top-16 by packed key (21-bit dist prefix | 11-bit
// index); merge recomputes exact f32 distances (stable (d,j) order). Then the
// 256 merge threads run the per-point geometry (cov over L=8, 5x QR with
// LAPACK Householder convention, dc projection + sign fix + normalize)
// directly from LDS cloud -> bit-identical to the former geom_kernel.
__global__ __launch_bounds__(1024) void knn_geom_kernel(const float* __restrict__ pos,
                                                        float* __restrict__ dcn) {
    __shared__ float4 cloud[P_];                 // 32 KB
    __shared__ unsigned short lists[1024 * 16];  // 32 KB, [seg][q][16]
    int b = blockIdx.x >> 3, tile = blockIdx.x & 7;
    int base = b * P_;
    int t = threadIdx.x;
    for (int j = t; j < P_; j += 1024) {
        float x = pos[(base + j) * 3 + 0];
        float y = pos[(base + j) * 3 + 1];
        float z = pos[(base + j) * 3 + 2];
        cloud[j] = make_float4(x, y, z, x * x + y * y + z * z);
    }
    __syncthreads();

    int seg = t >> 8, q = t & 255;
    int il = tile * 256 + q;
    float4 Q = cloud[il];
    float nx = -2.f * Q.x, ny = -2.f * Q.y, nz = -2.f * Q.z, qs = Q.w;

    unsigned bu[16];
#pragma unroll
    for (int m = 0; m < 16; m++) bu[m] = 0xFFFFFFFFu;
    // depth-6 lazy accept buffer of packed keys (static-indexed shift register)
    unsigned e0 = ~0u, e1 = ~0u, e2 = ~0u, e3 = ~0u, e4 = ~0u, e5 = ~0u;
    int cnt = 0;
    unsigned thr = 0xFFFFFFFFu;                  // stale-but-safe packed threshold

    int j0 = seg << 9;
    float4 C = cloud[j0];
    for (int jj = 0; jj < 512; jj++) {
        float4 Cn = cloud[j0 + jj + 1];   // prefetch; last iter reads into
                                          // lists region: garbage, never used
        int j = j0 + jj;
        float d = distf(C, nx, ny, nz, qs);
        unsigned key = (__float_as_uint(fmaxf(d, 0.f)) & 0xFFFFF800u) | (unsigned)j;
        bool acc = (key < thr) && (j != il);
        e5 = acc ? e4 : e5;
        e4 = acc ? e3 : e4;
        e3 = acc ? e2 : e3;
        e2 = acc ? e1 : e2;
        e1 = acc ? e0 : e1;
        e0 = acc ? key : e0;
        cnt += acc;
        if (__any(cnt >= 6)) {
            insU(bu, e5); insU(bu, e4); insU(bu, e3);
            insU(bu, e2); insU(bu, e1); insU(bu, e0);
            e0 = e1 = e2 = e3 = e4 = e5 = 0xFFFFFFFFu;
            cnt = 0;
            thr = bu[15];
        }
        C = Cn;
    }
    insU(bu, e5); insU(bu, e4); insU(bu, e3);
    insU(bu, e2); insU(bu, e1); insU(bu, e0);

#pragma unroll
    for (int m = 0; m < 16; m++) lists[t * 16 + m] = (unsigned short)(bu[m] & 0x7FFu);
    __syncthreads();

    if (t >= 256) return;

    // ---- merge: exact distances, stable order ----
    int il2 = tile * 256 + t;
    float4 Q2 = cloud[il2];
    float nx2 = -2.f * Q2.x, ny2 = -2.f * Q2.y, nz2 = -2.f * Q2.z, qs2 = Q2.w;
    float md[16]; int mi[16];
#pragma unroll
    for (int m = 0; m < 16; m++) { md[m] = INFINITY; mi[m] = 0; }
    for (int s = 0; s < 4; s++) {
#pragma unroll
        for (int r = 0; r < 16; r++) {
            int j = lists[((s << 8) | t) * 16 + r];
            float4 Cm = cloud[j];
            insert16(md, mi, distf(Cm, nx2, ny2, nz2, qs2), j);
        }
    }

    // ---- geometry (formerly geom_kernel), positions from LDS ----
    float px = Q2.x, py = Q2.y, pz = Q2.z;
    float cx[K_], cy[K_], cz[K_];
#pragma unroll
    for (int k = 0; k < K_; k++) {
        float4 Cv = cloud[mi[k]];
        cx[k] = Cv.x - px;
        cy[k] = Cv.y - py;
        cz[k] = Cv.z - pz;
    }
    float A[3][3];
    {
        float a00 = 0, a01 = 0, a02 = 0, a11 = 0, a12 = 0, a22 = 0;
#pragma unroll
        for (int l = 0; l < L_; l++) {
            a00 += cx[l] * cx[l]; a01 += cx[l] * cy[l]; a02 += cx[l] * cz[l];
            a11 += cy[l] * cy[l]; a12 += cy[l] * cz[l]; a22 += cz[l] * cz[l];
        }
        A[0][0] = a00; A[0][1] = a01; A[0][2] = a02;
        A[1][0] = a01; A[1][1] = a11; A[1][2] = a12;
        A[2][0] = a02; A[2][1] = a12; A[2][2] = a22;
    }
    float Vt[3][3] = {{1.f, 0.f, 0.f}, {0.f, 1.f, 0.f}, {0.f, 0.f, 1.f}};

    for (int it = 0; it < 5; it++) {
        float M00 = A[0][0], M01 = A[0][1], M02 = A[0][2];
        float M10 = A[1][0], M11 = A[1][1], M12 = A[1][2];
        float M20 = A[2][0], M21 = A[2][1], M22 = A[2][2];
        float tau0 = 0.f, v1 = 0.f, v2 = 0.f;
        float xn2 = M10 * M10 + M20 * M20;
        if (xn2 != 0.f) {
            float beta = -copysignf(sqrtf(M00 * M00 + xn2), M00);
            tau0 = (beta - M00) / beta;
            float inv = 1.f / (M00 - beta);
            v1 = M10 * inv; v2 = M20 * inv;
            float s;
            s = tau0 * (M01 + v1 * M11 + v2 * M21); M01 -= s; M11 -= v1 * s; M21 -= v2 * s;
            s = tau0 * (M02 + v1 * M12 + v2 * M22); M02 -= s; M12 -= v1 * s; M22 -= v2 * s;
            M00 = beta;
        }
        float tau1 = 0.f, u2 = 0.f;
        if (M21 != 0.f) {
            float beta1 = -copysignf(sqrtf(M11 * M11 + M21 * M21), M11);
            tau1 = (beta1 - M11) / beta1;
            u2 = M21 / (M11 - beta1);
            float s = tau1 * (M12 + u2 * M22); M12 -= s; M22 -= u2 * s;
            M11 = beta1;
        }
        float h11 = 1.f - tau1, h12 = -tau1 * u2, h22 = 1.f - tau1 * u2 * u2;
        float Qm[3][3];
        Qm[0][0] = 1.f - tau0;
        Qm[1][0] = -v1 * tau0;
        Qm[2][0] = -v2 * tau0;
        float t1 = tau0 * (v1 * h11 + v2 * h12);
        Qm[0][1] = -t1;
        Qm[1][1] = h11 - v1 * t1;
        Qm[2][1] = h12 - v2 * t1;
        float t2 = tau0 * (v1 * h12 + v2 * h22);
        Qm[0][2] = -t2;
        Qm[1][2] = h12 - v1 * t2;
        Qm[2][2] = h22 - v2 * t2;
        A[0][0] = M00 * Qm[0][0] + M01 * Qm[1][0] + M02 * Qm[2][0];
        A[0][1] = M00 * Qm[0][1] + M01 * Qm[1][1] + M02 * Qm[2][1];
        A[0][2] = M00 * Qm[0][2] + M01 * Qm[1][2] + M02 * Qm[2][2];
        A[1][0] = M11 * Qm[1][0] + M12 * Qm[2][0];
        A[1][1] = M11 * Qm[1][1] + M12 * Qm[2][1];
        A[1][2] = M11 * Qm[1][2] + M12 * Qm[2][2];
        A[2][0] = M22 * Qm[2][0];
        A[2][1] = M22 * Qm[2][1];
        A[2][2] = M22 * Qm[2][2];
        float nv[3][3];
#pragma unroll
        for (int r = 0; r < 3; r++)
#pragma unroll
            for (int c = 0; c < 3; c++)
                nv[r][c] = Vt[r][0] * Qm[0][c] + Vt[r][1] * Qm[1][c] + Vt[r][2] * Qm[2][c];
#pragma unroll
        for (int r = 0; r < 3; r++)
#pragma unroll
            for (int c = 0; c < 3; c++) Vt[r][c] = nv[r][c];
    }

    float s2 = 0.f, mx01 = 0.f, mx2 = 0.f;
#pragma unroll
    for (int k = 0; k < K_; k++) {
        float d0 = cx[k] * Vt[0][0] + cy[k] * Vt[1][0] + cz[k] * Vt[2][0];
        float d1 = cx[k] * Vt[0][1] + cy[k] * Vt[1][1] + cz[k] * Vt[2][1];
        float d2 = cx[k] * Vt[0][2] + cy[k] * Vt[1][2] + cz[k] * Vt[2][2];
        s2 += d2;
        mx01 = fmaxf(mx01, fmaxf(fabsf(d0), fabsf(d1)));
        mx2  = fmaxf(mx2, fabsf(d2));
    }
    float sg = (s2 > 0.f) ? 1.f : ((s2 < 0.f) ? -1.f : 0.f);
    float mx = fmaxf(mx01, (sg == 0.f) ? 0.f : mx2);
    float hs = 0.5f / mx;
    float o[48];
#pragma unroll
    for (int k = 0; k < K_; k++) {
        float d0 = cx[k] * Vt[0][0] + cy[k] * Vt[1][0] + cz[k] * Vt[2][0];
        float d1 = cx[k] * Vt[0][1] + cy[k] * Vt[1][1] + cz[k] * Vt[2][1];
        float d2 = (cx[k] * Vt[0][2] + cy[k] * Vt[1][2] + cz[k] * Vt[2][2]) * sg;
        o[k * 3 + 0] = d0 * hs + 0.5f;
        o[k * 3 + 1] = d1 * hs + 0.5f;
        o[k * 3 + 2] = d2 * hs + 0.5f;
    }
    int i = base + il2;
    float4* row = (float4*)(dcn + (size_t)i * 48);
#pragma unroll
    for (int m = 0; m < 12; m++)
        row[m] = make_float4(o[m * 4 + 0], o[m * 4 + 1], o[m * 4 + 2], o[m * 4 + 3]);
}

// ---------- Kernel 2: trilinear spline gather + out_nondir + BN partials -----
__global__ __launch_bounds__(256) void spline_kernel(const float* __restrict__ dcn,
                                                     const float* __restrict__ w_spline,
                                                     const float* __restrict__ w_root,
                                                     const float* __restrict__ b_spline,
                                                     float* __restrict__ x,
                                                     float* __restrict__ partials) {
    __shared__ float ws_t[F_ * KS3_];   // [f][cell], 32000 B
    __shared__ float red[4][64];
    {
        int f = threadIdx.x & 63;
        for (int c = threadIdx.x >> 6; c < KS3_; c += 4)
            ws_t[f * KS3_ + c] = w_spline[c * 64 + f];
    }
    __syncthreads();
    int wave = threadIdx.x >> 6, f = threadIdx.x & 63;
    const float* wbase = &ws_t[f * KS3_];
    float wr = w_root[f] + b_spline[f];
    float s1 = 0.f, s2 = 0.f;
    for (int p = 0; p < 16; p++) {
        int i = blockIdx.x * 64 + wave * 16 + p;
        const float4* row = (const float4*)(dcn + (size_t)i * 48);
        float pr[48];
#pragma unroll
        for (int m = 0; m < 12; m++) {
            float4 v = row[m];
            pr[m * 4 + 0] = v.x; pr[m * 4 + 1] = v.y;
            pr[m * 4 + 2] = v.z; pr[m * 4 + 3] = v.w;
        }
        float acc = 0.f;
#pragma unroll
        for (int k = 0; k < K_; k++) {
            float p0 = pr[k * 3 + 0] * 4.f;
            float p1 = pr[k * 3 + 1] * 4.f;
            float p2 = pr[k * 3 + 2] * 4.f;
            float i0 = fminf(fmaxf(floorf(p0), 0.f), 3.f);
            float i1 = fminf(fmaxf(floorf(p1), 0.f), 3.f);
            float i2 = fminf(fmaxf(floorf(p2), 0.f), 3.f);
            float f0 = p0 - i0, f1 = p1 - i1, f2 = p2 - i2;
            float g0 = 1.f - f0, g1 = 1.f - f1, g2 = 1.f - f2;
            int c = (int)i0 + 5 * (int)i1 + 25 * (int)i2;
            const float* wp = wbase + c;
            float a0 = wp[0],  a1 = wp[1];
            float b0 = wp[5],  b1v = wp[6];
            float c0 = wp[25], c1 = wp[26];
            float d0 = wp[30], d1 = wp[31];
            float wA = g1 * g2, wB = f1 * g2, wC = g1 * f2, wD = f1 * f2;
            acc = fmaf(wA, fmaf(f0, a1, g0 * a0), acc);
            acc = fmaf(wB, fmaf(f0, b1v, g0 * b0), acc);
            acc = fmaf(wC, fmaf(f0, c1, g0 * c0), acc);
            acc = fmaf(wD, fmaf(f0, d1, g0 * d0), acc);
        }
        float xv = acc * (1.f / 16.f) + wr;
        x[(size_t)i * 64 + f] = xv;
        s1 += xv; s2 += xv * xv;
    }
    red[wave][f] = s1; __syncthreads();
    if (threadIdx.x < 64)
        partials[blockIdx.x * 128 + f] = red[0][f] + red[1][f] + red[2][f] + red[3][f];
    __syncthreads();
    red[wave][f] = s2; __syncthreads();
    if (threadIdx.x < 64)
        partials[blockIdx.x * 128 + 64 + f] = red[0][f] + red[1][f] + red[2][f] + red[3][f];
}

// ----------------------- Kernel 3: BN stats finalize -------------------------
__global__ __launch_bounds__(256) void stats_kernel(const float* __restrict__ partials,
                                                    const float* __restrict__ gamma,
                                                    const float* __restrict__ beta,
                                                    float* __restrict__ stats) {
    __shared__ double red1[256], red2[256];
    int t = threadIdx.x;
    int f = t & 63, g = t >> 6;
    double s1 = 0.0, s2 = 0.0;
    for (int b2 = g; b2 < 1024; b2 += 4) {
        s1 += (double)partials[b2 * 128 + f];
        s2 += (double)partials[b2 * 128 + 64 + f];
    }
    red1[t] = s1; red2[t] = s2;
    __syncthreads();
    if (t < 64) {
        double S1 = red1[t] + red1[t + 64] + red1[t + 128] + red1[t + 192];
        double S2 = red2[t] + red2[t + 64] + red2[t + 128] + red2[t + 192];
        double mu = S1 / (double)N_;
        double var = S2 / (double)N_ - mu * mu;
        double scale = (double)gamma[t] / sqrt(var + (double)EPS_);
        double shift = (double)beta[t] - mu * scale;
        stats[t] = (float)scale;
        stats[64 + t] = (float)shift;
    }
}

// -------------- Kernel 4: sigmoid + per-batch-chunk partial pool -------------
__global__ __launch_bounds__(256) void pool_partial_kernel(const float* __restrict__ x,
                                                           const float* __restrict__ stats,
                                                           float* __restrict__ pp) {
    __shared__ float red[4][64];
    int blk = blockIdx.x;
    int b = blk >> 3, ch = blk & 7;
    int f = threadIdx.x & 63, w = threadIdx.x >> 6;
    float scale = stats[f], shift = stats[64 + f];
    float acc = 0.f;
    int row0 = b * P_ + ch * 256;
    for (int r = w; r < 256; r += 4) {
        float v = x[(size_t)(row0 + r) * 64 + f];
        float t = v * scale + shift;
        acc += 1.f / (1.f + expf(-t));
    }
    red[w][f] = acc; __syncthreads();
    if (threadIdx.x < 64) pp[blk * 64 + f] = red[0][f] + red[1][f] + red[2][f] + red[3][f];
}

// --------- Kernel 5: batch means + MLP + log_softmax (1 block, fused) --------
__global__ __launch_bounds__(256) void tail_kernel(const float* __restrict__ pp,
                                                   const float* __restrict__ w1,
                                                   const float* __restrict__ b1,
                                                   const float* __restrict__ w2,
                                                   const float* __restrict__ b2,
                                                   float* __restrict__ out) {
    __shared__ float sy[B_ * F_];
    __shared__ float sy1[B_ * H_];
    __shared__ float sy2[B_ * NC_];
    for (int idx = threadIdx.x; idx < B_ * F_; idx += 256) {
        int b = idx >> 6, f = idx & 63;
        float s = 0.f;
#pragma unroll
        for (int g = 0; g < 8; g++) s += pp[(b * 8 + g) * 64 + f];
        sy[idx] = s * (1.f / 2048.f);
    }
    __syncthreads();
    for (int idx = threadIdx.x; idx < B_ * H_; idx += 256) {
        int b = idx >> 8, j = idx & 255;
        float acc = b1[j];
#pragma unroll 8
        for (int c = 0; c < F_; c++) acc += sy[b * 64 + c] * w1[c * 256 + j];
        sy1[idx] = acc > 0.f ? acc : expm1f(acc);
    }
    __syncthreads();
    for (int idx = threadIdx.x; idx < B_ * NC_; idx += 256) {
        int b = idx / NC_, j = idx % NC_;
        float acc = b2[j];
#pragma unroll 8
        for (int c = 0; c < H_; c++) acc += sy1[b * 256 + c] * w2[c * 40 + j];
        sy2[idx] = acc;
    }
    __syncthreads();
    if (threadIdx.x < B_) {
        int b = threadIdx.x;
        float m = -INFINITY;
        for (int j = 0; j < NC_; j++) m = fmaxf(m, sy2[b * NC_ + j]);
        float s = 0.f;
        for (int j = 0; j < NC_; j++) s += expf(sy2[b * NC_ + j] - m);
        float lse = logf(s);
        for (int j = 0; j < NC_; j++) out[b * NC_ + j] = sy2[b * NC_ + j] - m - lse;
    }
}

extern "C" void kernel_launch(void* const* d_in, const int* in_sizes, int n_in,
                              void* d_out, int out_size, void* d_ws, size_t ws_size,
                              hipStream_t stream) {
    const float* pos      = (const float*)d_in[0];
    const float* w_spline = (const float*)d_in[2];
    const float* w_root   = (const float*)d_in[3];
    const float* b_spline = (const float*)d_in[4];
    const float* bn_gamma = (const float*)d_in[5];
    const float* bn_beta  = (const float*)d_in[6];
    const float* w1       = (const float*)d_in[7];
    const float* b1       = (const float*)d_in[8];
    const float* w2       = (const float*)d_in[9];
    const float* b2       = (const float*)d_in[10];
    float* out = (float*)d_out;

    char* ws = (char*)d_ws;
    float* dcn      = (float*)(ws + 0);                    // 12 MB
    float* x        = (float*)(ws + (12u << 20));          // 16 MB
    float* partials = (float*)(ws + (28u << 20));          // 512 KB
    float* stats    = (float*)(ws + (28u << 20) + (512u << 10));        // 512 B
    float* pp       = (float*)(ws + (28u << 20) + (512u << 10) + 4096); // 64 KB

    knn_geom_kernel<<<B_ * 8, 1024, 0, stream>>>(pos, dcn);
    spline_kernel<<<N_ / 64, 256, 0, stream>>>(dcn, w_spline, w_root, b_spline, x, partials);
    stats_kernel<<<1, 256, 0, stream>>>(partials, bn_gamma, bn_beta, stats);
    pool_partial_kernel<<<B_ * 8, 256, 0, stream>>>(x, stats, pp);
    tail_kernel<<<1, 256, 0, stream>>>(pp, w1, b1, w2, b2, out);
}

// Round 6
// 261.141 us; speedup vs baseline: 4.3026x; 1.4354x over previous
//
#include <hip/hip_runtime.h>
#include <math.h>

#define B_ 32
#define P_ 2048
#define N_ 65536
#define K_ 16
#define L_ 8
#define F_ 64
#define KS_ 5
#define KS3_ 125
#define NC_ 40
#define H_ 256
#define EPS_ 1e-5f

// exact same fp expression used in scan and merge (pinned fmaf order)
__device__ __forceinline__ float distf(float4 C, float nx, float ny, float nz, float qs) {
    return fmaf(C.x, nx, fmaf(C.y, ny, fmaf(C.z, nz, C.w))) + qs;
}

// packed-key insertion: pure min/max chain, 2 inst per slot
__device__ __forceinline__ void insU(unsigned (&bu)[16], unsigned k) {
#pragma unroll
    for (int m = 0; m < 16; m++) {
        unsigned mn = min(bu[m], k);
        k = max(bu[m], k);
        bu[m] = mn;
    }
}

// exact (float,int) sorted insertion for the merge phase
__device__ __forceinline__ void insert16(float (&bd)[16], int (&bi)[16], float cd, int ci) {
#pragma unroll
    for (int m = 0; m < 16; m++) {
        bool sw = cd < bd[m];
        float td = sw ? bd[m] : cd;
        int   ti = sw ? bi[m] : ci;
        bd[m] = sw ? cd : bd[m];
        bi[m] = sw ? ci : bi[m];
        cd = td; ci = ti;
    }
}

// ------- Kernel 1: KNN (4 segments/query, shared threshold) + geom (fused) ---
// Scan selects per-segment top-16 by packed key (21-bit dist prefix | 11-bit
// index). The 4 segment threads of a query share a threshold via LDS
// atomicMin: every posted bu[15] is >= that segment's true 16th >= union
// 16th, so no true union-top-16 element is ever rejected (keys are unique ->
// strict < test is safe). Starved segments (<16 real accepts) emit 0xFFFF
// fillers, skipped at merge. Merge recomputes exact f32 distances (stable
// (d,j) order), then runs cov/QR/dc geometry from LDS cloud.
__global__ __launch_bounds__(1024) void knn_geom_kernel(const float* __restrict__ pos,
                                                        float* __restrict__ dcn) {
    __shared__ float4 cloud[P_];                 // 32 KB
    __shared__ unsigned short lists[1024 * 16];  // 32 KB, [seg][q][16]
    __shared__ unsigned sthr[256];               // shared per-query threshold
    int b = blockIdx.x >> 3, tile = blockIdx.x & 7;
    int base = b * P_;
    int t = threadIdx.x;
    for (int j = t; j < P_; j += 1024) {
        float x = pos[(base + j) * 3 + 0];
        float y = pos[(base + j) * 3 + 1];
        float z = pos[(base + j) * 3 + 2];
        cloud[j] = make_float4(x, y, z, x * x + y * y + z * z);
    }
    if (t < 256) sthr[t] = 0xFFFFFFFFu;
    __syncthreads();

    int seg = t >> 8, q = t & 255;
    int il = tile * 256 + q;
    float4 Q = cloud[il];
    float nx = -2.f * Q.x, ny = -2.f * Q.y, nz = -2.f * Q.z, qs = Q.w;

    unsigned bu[16];
#pragma unroll
    for (int m = 0; m < 16; m++) bu[m] = 0xFFFFFFFFu;
    // depth-6 lazy accept buffer of packed keys (static-indexed shift register)
    unsigned e0 = ~0u, e1 = ~0u, e2 = ~0u, e3 = ~0u, e4 = ~0u, e5 = ~0u;
    int cnt = 0;
    unsigned thr = 0xFFFFFFFFu;

    int j0 = seg << 9;
    float4 C = cloud[j0];
    for (int jj = 0; jj < 512; jj++) {
        float4 Cn = cloud[j0 + jj + 1];   // prefetch; last iter reads into
                                          // lists region: garbage, never used
        int j = j0 + jj;
        float d = distf(C, nx, ny, nz, qs);
        unsigned key = (__float_as_uint(fmaxf(d, 0.f)) & 0xFFFFF800u) | (unsigned)j;
        bool acc = (key < thr) && (j != il);
        e5 = acc ? e4 : e5;
        e4 = acc ? e3 : e4;
        e3 = acc ? e2 : e3;
        e2 = acc ? e1 : e2;
        e1 = acc ? e0 : e1;
        e0 = acc ? key : e0;
        cnt += acc;
        if (__any(cnt >= 6)) {
            insU(bu, e5); insU(bu, e4); insU(bu, e3);
            insU(bu, e2); insU(bu, e1); insU(bu, e0);
            e0 = e1 = e2 = e3 = e4 = e5 = 0xFFFFFFFFu;
            cnt = 0;
            unsigned o = atomicMin(&sthr[q], bu[15]);
            thr = min(o, bu[15]);
        }
        C = Cn;
    }
    insU(bu, e5); insU(bu, e4); insU(bu, e3);
    insU(bu, e2); insU(bu, e1); insU(bu, e0);

#pragma unroll
    for (int m = 0; m < 16; m++) {
        unsigned v = bu[m];
        lists[t * 16 + m] = (v == 0xFFFFFFFFu) ? (unsigned short)0xFFFFu
                                               : (unsigned short)(v & 0x7FFu);
    }
    __syncthreads();

    if (t >= 256) return;

    // ---- merge: exact distances, stable order ----
    int il2 = tile * 256 + t;
    float4 Q2 = cloud[il2];
    float nx2 = -2.f * Q2.x, ny2 = -2.f * Q2.y, nz2 = -2.f * Q2.z, qs2 = Q2.w;
    float md[16]; int mi[16];
#pragma unroll
    for (int m = 0; m < 16; m++) { md[m] = INFINITY; mi[m] = 0; }
    for (int s = 0; s < 4; s++) {
#pragma unroll
        for (int r = 0; r < 16; r++) {
            int jr = lists[((s << 8) | t) * 16 + r];
            int j = jr & 0x7FF;
            float4 Cm = cloud[j];
            float dm = (jr == 0xFFFF) ? INFINITY : distf(Cm, nx2, ny2, nz2, qs2);
            insert16(md, mi, dm, j);
        }
    }

    // ---- geometry (cov over L=8, 5x QR, dc), positions from LDS ----
    float px = Q2.x, py = Q2.y, pz = Q2.z;
    float cx[K_], cy[K_], cz[K_];
#pragma unroll
    for (int k = 0; k < K_; k++) {
        float4 Cv = cloud[mi[k]];
        cx[k] = Cv.x - px;
        cy[k] = Cv.y - py;
        cz[k] = Cv.z - pz;
    }
    float A[3][3];
    {
        float a00 = 0, a01 = 0, a02 = 0, a11 = 0, a12 = 0, a22 = 0;
#pragma unroll
        for (int l = 0; l < L_; l++) {
            a00 += cx[l] * cx[l]; a01 += cx[l] * cy[l]; a02 += cx[l] * cz[l];
            a11 += cy[l] * cy[l]; a12 += cy[l] * cz[l]; a22 += cz[l] * cz[l];
        }
        A[0][0] = a00; A[0][1] = a01; A[0][2] = a02;
        A[1][0] = a01; A[1][1] = a11; A[1][2] = a12;
        A[2][0] = a02; A[2][1] = a12; A[2][2] = a22;
    }
    float Vt[3][3] = {{1.f, 0.f, 0.f}, {0.f, 1.f, 0.f}, {0.f, 0.f, 1.f}};

    for (int it = 0; it < 5; it++) {
        float M00 = A[0][0], M01 = A[0][1], M02 = A[0][2];
        float M10 = A[1][0], M11 = A[1][1], M12 = A[1][2];
        float M20 = A[2][0], M21 = A[2][1], M22 = A[2][2];
        float tau0 = 0.f, v1 = 0.f, v2 = 0.f;
        float xn2 = M10 * M10 + M20 * M20;
        if (xn2 != 0.f) {
            float beta = -copysignf(sqrtf(M00 * M00 + xn2), M00);
            tau0 = (beta - M00) / beta;
            float inv = 1.f / (M00 - beta);
            v1 = M10 * inv; v2 = M20 * inv;
            float s;
            s = tau0 * (M01 + v1 * M11 + v2 * M21); M01 -= s; M11 -= v1 * s; M21 -= v2 * s;
            s = tau0 * (M02 + v1 * M12 + v2 * M22); M02 -= s; M12 -= v1 * s; M22 -= v2 * s;
            M00 = beta;
        }
        float tau1 = 0.f, u2 = 0.f;
        if (M21 != 0.f) {
            float beta1 = -copysignf(sqrtf(M11 * M11 + M21 * M21), M11);
            tau1 = (beta1 - M11) / beta1;
            u2 = M21 / (M11 - beta1);
            float s = tau1 * (M12 + u2 * M22); M12 -= s; M22 -= u2 * s;
            M11 = beta1;
        }
        float h11 = 1.f - tau1, h12 = -tau1 * u2, h22 = 1.f - tau1 * u2 * u2;
        float Qm[3][3];
        Qm[0][0] = 1.f - tau0;
        Qm[1][0] = -v1 * tau0;
        Qm[2][0] = -v2 * tau0;
        float t1 = tau0 * (v1 * h11 + v2 * h12);
        Qm[0][1] = -t1;
        Qm[1][1] = h11 - v1 * t1;
        Qm[2][1] = h12 - v2 * t1;
        float t2 = tau0 * (v1 * h12 + v2 * h22);
        Qm[0][2] = -t2;
        Qm[1][2] = h12 - v1 * t2;
        Qm[2][2] = h22 - v2 * t2;
        A[0][0] = M00 * Qm[0][0] + M01 * Qm[1][0] + M02 * Qm[2][0];
        A[0][1] = M00 * Qm[0][1] + M01 * Qm[1][1] + M02 * Qm[2][1];
        A[0][2] = M00 * Qm[0][2] + M01 * Qm[1][2] + M02 * Qm[2][2];
        A[1][0] = M11 * Qm[1][0] + M12 * Qm[2][0];
        A[1][1] = M11 * Qm[1][1] + M12 * Qm[2][1];
        A[1][2] = M11 * Qm[1][2] + M12 * Qm[2][2];
        A[2][0] = M22 * Qm[2][0];
        A[2][1] = M22 * Qm[2][1];
        A[2][2] = M22 * Qm[2][2];
        float nv[3][3];
#pragma unroll
        for (int r = 0; r < 3; r++)
#pragma unroll
            for (int c = 0; c < 3; c++)
                nv[r][c] = Vt[r][0] * Qm[0][c] + Vt[r][1] * Qm[1][c] + Vt[r][2] * Qm[2][c];
#pragma unroll
        for (int r = 0; r < 3; r++)
#pragma unroll
            for (int c = 0; c < 3; c++) Vt[r][c] = nv[r][c];
    }

    float s2 = 0.f, mx01 = 0.f, mx2 = 0.f;
#pragma unroll
    for (int k = 0; k < K_; k++) {
        float d0 = cx[k] * Vt[0][0] + cy[k] * Vt[1][0] + cz[k] * Vt[2][0];
        float d1 = cx[k] * Vt[0][1] + cy[k] * Vt[1][1] + cz[k] * Vt[2][1];
        float d2 = cx[k] * Vt[0][2] + cy[k] * Vt[1][2] + cz[k] * Vt[2][2];
        s2 += d2;
        mx01 = fmaxf(mx01, fmaxf(fabsf(d0), fabsf(d1)));
        mx2  = fmaxf(mx2, fabsf(d2));
    }
    float sg = (s2 > 0.f) ? 1.f : ((s2 < 0.f) ? -1.f : 0.f);
    float mx = fmaxf(mx01, (sg == 0.f) ? 0.f : mx2);
    float hs = 0.5f / mx;
    float o[48];
#pragma unroll
    for (int k = 0; k < K_; k++) {
        float d0 = cx[k] * Vt[0][0] + cy[k] * Vt[1][0] + cz[k] * Vt[2][0];
        float d1 = cx[k] * Vt[0][1] + cy[k] * Vt[1][1] + cz[k] * Vt[2][1];
        float d2 = (cx[k] * Vt[0][2] + cy[k] * Vt[1][2] + cz[k] * Vt[2][2]) * sg;
        o[k * 3 + 0] = d0 * hs + 0.5f;
        o[k * 3 + 1] = d1 * hs + 0.5f;
        o[k * 3 + 2] = d2 * hs + 0.5f;
    }
    int i = base + il2;
    float4* row = (float4*)(dcn + (size_t)i * 48);
#pragma unroll
    for (int m = 0; m < 12; m++)
        row[m] = make_float4(o[m * 4 + 0], o[m * 4 + 1], o[m * 4 + 2], o[m * 4 + 3]);
}

// ---------- Kernel 2: trilinear spline gather + out_nondir + BN partials -----
__global__ __launch_bounds__(256) void spline_kernel(const float* __restrict__ dcn,
                                                     const float* __restrict__ w_spline,
                                                     const float* __restrict__ w_root,
                                                     const float* __restrict__ b_spline,
                                                     float* __restrict__ x,
                                                     float* __restrict__ partials) {
    __shared__ float ws_t[F_ * KS3_];   // [f][cell], 32000 B
    __shared__ float red[4][64];
    {
        int f = threadIdx.x & 63;
        for (int c = threadIdx.x >> 6; c < KS3_; c += 4)
            ws_t[f * KS3_ + c] = w_spline[c * 64 + f];
    }
    __syncthreads();
    int wave = threadIdx.x >> 6, f = threadIdx.x & 63;
    const float* wbase = &ws_t[f * KS3_];
    float wr = w_root[f] + b_spline[f];
    float s1 = 0.f, s2 = 0.f;
    for (int p = 0; p < 16; p++) {
        int i = blockIdx.x * 64 + wave * 16 + p;
        const float4* row = (const float4*)(dcn + (size_t)i * 48);
        float pr[48];
#pragma unroll
        for (int m = 0; m < 12; m++) {
            float4 v = row[m];
            pr[m * 4 + 0] = v.x; pr[m * 4 + 1] = v.y;
            pr[m * 4 + 2] = v.z; pr[m * 4 + 3] = v.w;
        }
        float acc = 0.f;
#pragma unroll
        for (int k = 0; k < K_; k++) {
            float p0 = pr[k * 3 + 0] * 4.f;
            float p1 = pr[k * 3 + 1] * 4.f;
            float p2 = pr[k * 3 + 2] * 4.f;
            float i0 = fminf(fmaxf(floorf(p0), 0.f), 3.f);
            float i1 = fminf(fmaxf(floorf(p1), 0.f), 3.f);
            float i2 = fminf(fmaxf(floorf(p2), 0.f), 3.f);
            float f0 = p0 - i0, f1 = p1 - i1, f2 = p2 - i2;
            float g0 = 1.f - f0, g1 = 1.f - f1, g2 = 1.f - f2;
            int c = (int)i0 + 5 * (int)i1 + 25 * (int)i2;
            const float* wp = wbase + c;
            float a0 = wp[0],  a1 = wp[1];
            float b0 = wp[5],  b1v = wp[6];
            float c0 = wp[25], c1 = wp[26];
            float d0 = wp[30], d1 = wp[31];
            float wA = g1 * g2, wB = f1 * g2, wC = g1 * f2, wD = f1 * f2;
            acc = fmaf(wA, fmaf(f0, a1, g0 * a0), acc);
            acc = fmaf(wB, fmaf(f0, b1v, g0 * b0), acc);
            acc = fmaf(wC, fmaf(f0, c1, g0 * c0), acc);
            acc = fmaf(wD, fmaf(f0, d1, g0 * d0), acc);
        }
        float xv = acc * (1.f / 16.f) + wr;
        x[(size_t)i * 64 + f] = xv;
        s1 += xv; s2 += xv * xv;
    }
    red[wave][f] = s1; __syncthreads();
    if (threadIdx.x < 64)
        partials[blockIdx.x * 128 + f] = red[0][f] + red[1][f] + red[2][f] + red[3][f];
    __syncthreads();
    red[wave][f] = s2; __syncthreads();
    if (threadIdx.x < 64)
        partials[blockIdx.x * 128 + 64 + f] = red[0][f] + red[1][f] + red[2][f] + red[3][f];
}

// ----------------------- Kernel 3: BN stats finalize -------------------------
__global__ __launch_bounds__(256) void stats_kernel(const float* __restrict__ partials,
                                                    const float* __restrict__ gamma,
                                                    const float* __restrict__ beta,
                                                    float* __restrict__ stats) {
    __shared__ double red1[256], red2[256];
    int t = threadIdx.x;
    int f = t & 63, g = t >> 6;
    double a0 = 0, a1 = 0, a2 = 0, a3 = 0, q0 = 0, q1 = 0, q2 = 0, q3 = 0;
    for (int b2 = g; b2 < 1024; b2 += 16) {
        a0 += (double)partials[(b2     ) * 128 + f];
        q0 += (double)partials[(b2     ) * 128 + 64 + f];
        a1 += (double)partials[(b2 +  4) * 128 + f];
        q1 += (double)partials[(b2 +  4) * 128 + 64 + f];
        a2 += (double)partials[(b2 +  8) * 128 + f];
        q2 += (double)partials[(b2 +  8) * 128 + 64 + f];
        a3 += (double)partials[(b2 + 12) * 128 + f];
        q3 += (double)partials[(b2 + 12) * 128 + 64 + f];
    }
    red1[t] = (a0 + a1) + (a2 + a3);
    red2[t] = (q0 + q1) + (q2 + q3);
    __syncthreads();
    if (t < 64) {
        double S1 = red1[t] + red1[t + 64] + red1[t + 128] + red1[t + 192];
        double S2 = red2[t] + red2[t + 64] + red2[t + 128] + red2[t + 192];
        double mu = S1 / (double)N_;
        double var = S2 / (double)N_ - mu * mu;
        double scale = (double)gamma[t] / sqrt(var + (double)EPS_);
        double shift = (double)beta[t] - mu * scale;
        stats[t] = (float)scale;
        stats[64 + t] = (float)shift;
    }
}

// -------------- Kernel 4: sigmoid + per-batch-chunk partial pool -------------
__global__ __launch_bounds__(256) void pool_partial_kernel(const float* __restrict__ x,
                                                           const float* __restrict__ stats,
                                                           float* __restrict__ pp) {
    __shared__ float red[4][64];
    int blk = blockIdx.x;            // 32 batches * 32 chunks of 64 rows
    int b = blk >> 5, ch = blk & 31;
    int f = threadIdx.x & 63, w = threadIdx.x >> 6;
    float scale = stats[f], shift = stats[64 + f];
    float acc = 0.f;
    int row0 = b * P_ + ch * 64;
    for (int r = w; r < 64; r += 4) {
        float v = x[(size_t)(row0 + r) * 64 + f];
        float t = fmaf(v, scale, shift);
        acc += __fdividef(1.f, 1.f + __expf(-t));
    }
    red[w][f] = acc; __syncthreads();
    if (threadIdx.x < 64) pp[blk * 64 + f] = red[0][f] + red[1][f] + red[2][f] + red[3][f];
}

// ------------------ Kernel 5: batch means + GEMM1 + ELU ----------------------
__global__ __launch_bounds__(256) void mlp1_kernel(const float* __restrict__ pp,
                                                   const float* __restrict__ w1,
                                                   const float* __restrict__ b1,
                                                   float* __restrict__ y1) {
    __shared__ float ssy[64];
    int b = blockIdx.x, t = threadIdx.x;
    if (t < 64) {
        float s = 0.f;
#pragma unroll
        for (int g = 0; g < 32; g++) s += pp[(b * 32 + g) * 64 + t];
        ssy[t] = s * (1.f / 2048.f);
    }
    __syncthreads();
    float acc = b1[t];
#pragma unroll 8
    for (int c = 0; c < F_; c++) acc = fmaf(ssy[c], w1[c * 256 + t], acc);
    y1[b * 256 + t] = acc > 0.f ? acc : expm1f(acc);
}

// ------------------ Kernel 6: GEMM2 + log_softmax (wave-wide) ----------------
__global__ __launch_bounds__(64) void mlp2_kernel(const float* __restrict__ y1,
                                                  const float* __restrict__ w2,
                                                  const float* __restrict__ b2,
                                                  float* __restrict__ out) {
    int b = blockIdx.x, j = threadIdx.x;
    float acc = -INFINITY;
    if (j < NC_) {
        acc = b2[j];
#pragma unroll 8
        for (int c = 0; c < H_; c++) acc = fmaf(y1[b * 256 + c], w2[c * 40 + j], acc);
    }
    float m = acc;
#pragma unroll
    for (int o = 32; o > 0; o >>= 1) m = fmaxf(m, __shfl_xor(m, o, 64));
    float e = (j < NC_) ? expf(acc - m) : 0.f;
    float s = e;
#pragma unroll
    for (int o = 32; o > 0; o >>= 1) s += __shfl_xor(s, o, 64);
    if (j < NC_) out[b * NC_ + j] = acc - m - logf(s);
}

extern "C" void kernel_launch(void* const* d_in, const int* in_sizes, int n_in,
                              void* d_out, int out_size, void* d_ws, size_t ws_size,
                              hipStream_t stream) {
    const float* pos      = (const float*)d_in[0];
    const float* w_spline = (const float*)d_in[2];
    const float* w_root   = (const float*)d_in[3];
    const float* b_spline = (const float*)d_in[4];
    const float* bn_gamma = (const float*)d_in[5];
    const float* bn_beta  = (const float*)d_in[6];
    const float* w1       = (const float*)d_in[7];
    const float* b1       = (const float*)d_in[8];
    const float* w2       = (const float*)d_in[9];
    const float* b2       = (const float*)d_in[10];
    float* out = (float*)d_out;

    char* ws = (char*)d_ws;
    float* dcn      = (float*)(ws + 0);                    // 12 MB
    float* x        = (float*)(ws + (12u << 20));          // 16 MB
    float* partials = (float*)(ws + (28u << 20));          // 512 KB
    float* stats    = (float*)(ws + (28u << 20) + (512u << 10));               // 4 KB slot
    float* pp       = (float*)(ws + (28u << 20) + (512u << 10) + 4096);        // 256 KB
    float* y1       = (float*)(ws + (28u << 20) + (512u << 10) + 4096 + (256u << 10)); // 32 KB

    knn_geom_kernel<<<B_ * 8, 1024, 0, stream>>>(pos, dcn);
    spline_kernel<<<N_ / 64, 256, 0, stream>>>(dcn, w_spline, w_root, b_spline, x, partials);
    stats_kernel<<<1, 256, 0, stream>>>(partials, bn_gamma, bn_beta, stats);
    pool_partial_kernel<<<B_ * 32, 256, 0, stream>>>(x, stats, pp);
    mlp1_kernel<<<B_, 256, 0, stream>>>(pp, w1, b1, y1);
    mlp2_kernel<<<B_, 64, 0, stream>>>(y1, w2, b2, out);
}

// Round 7
// 243.575 us; speedup vs baseline: 4.6129x; 1.0721x over previous
//
#include <hip/hip_runtime.h>
#include <math.h>

#define B_ 32
#define P_ 2048
#define N_ 65536
#define K_ 16
#define L_ 8
#define F_ 64
#define KS_ 5
#define KS3_ 125
#define NC_ 40
#define H_ 256
#define EPS_ 1e-5f

// exact same fp expression used in scan and merge (pinned fmaf order)
__device__ __forceinline__ float distf(float4 C, float nx, float ny, float nz, float qs) {
    return fmaf(C.x, nx, fmaf(C.y, ny, fmaf(C.z, nz, C.w))) + qs;
}

// packed-key insertion: pure min/max chain, 2 inst per slot
__device__ __forceinline__ void insU(unsigned (&bu)[16], unsigned k) {
#pragma unroll
    for (int m = 0; m < 16; m++) {
        unsigned mn = min(bu[m], k);
        k = max(bu[m], k);
        bu[m] = mn;
    }
}

// exact (float,int) sorted insertion for the merge phase
__device__ __forceinline__ void insert16(float (&bd)[16], int (&bi)[16], float cd, int ci) {
#pragma unroll
    for (int m = 0; m < 16; m++) {
        bool sw = cd < bd[m];
        float td = sw ? bd[m] : cd;
        int   ti = sw ? bi[m] : ci;
        bd[m] = sw ? cd : bd[m];
        bi[m] = sw ? ci : bi[m];
        cd = td; ci = ti;
    }
}

// Segment scan: top-16 by packed key (21-bit dist prefix | 11-bit index).
// Threshold shared across the 4 segment threads of a query via PLAIN relaxed
// LDS load/store (no atomic: any posted value is a valid upper bound on the
// union-16th; races only make the bound staler, never wrong; keys unique ->
// strict < is exact). Buffer-full detected by e5 becoming a real key (all
// real keys <= 0x7FFFFFFF). SELF: only the wave whose segment contains the
// block's queries tests j != il.
template<bool SELF>
__device__ __forceinline__ void scan_seg(const float4* cloud, unsigned* sthr,
                                         int j0, int il, int q,
                                         float nx, float ny, float nz, float qs,
                                         unsigned (&bu)[16]) {
    unsigned e0 = ~0u, e1 = ~0u, e2 = ~0u, e3 = ~0u, e4 = ~0u, e5 = ~0u;
    unsigned thr = 0xFFFFFFFFu;
    float4 C = cloud[j0];
    for (int jj = 0; jj < 512; jj++) {
        float4 Cn = cloud[j0 + jj + 1];   // prefetch; last iter reads past cloud
                                          // into lists region: garbage, never used
        int j = j0 + jj;
        float d = distf(C, nx, ny, nz, qs);
        unsigned key = (__float_as_uint(fmaxf(d, 0.f)) & 0xFFFFF800u) | (unsigned)j;
        bool acc = (key < thr);
        if (SELF) acc = acc && (j != il);
        e5 = acc ? e4 : e5;
        e4 = acc ? e3 : e4;
        e3 = acc ? e2 : e3;
        e2 = acc ? e1 : e2;
        e1 = acc ? e0 : e1;
        e0 = acc ? key : e0;
        if (__any(e5 != 0xFFFFFFFFu)) {   // 6th accept since last flush
            unsigned o = __hip_atomic_load(&sthr[q], __ATOMIC_RELAXED,
                                           __HIP_MEMORY_SCOPE_WORKGROUP);
            insU(bu, e5); insU(bu, e4); insU(bu, e3);
            insU(bu, e2); insU(bu, e1); insU(bu, e0);
            e0 = e1 = e2 = e3 = e4 = e5 = 0xFFFFFFFFu;
            thr = min(min(bu[15], o), thr);
            __hip_atomic_store(&sthr[q], thr, __ATOMIC_RELAXED,
                               __HIP_MEMORY_SCOPE_WORKGROUP);
        }
        C = Cn;
    }
    insU(bu, e5); insU(bu, e4); insU(bu, e3);
    insU(bu, e2); insU(bu, e1); insU(bu, e0);
}

// ------- Kernel 1: KNN (4 segments/query, shared threshold) + geom (fused) ---
__global__ __launch_bounds__(1024) void knn_geom_kernel(const float* __restrict__ pos,
                                                        float* __restrict__ dcn) {
    __shared__ float4 cloud[P_];                 // 32 KB
    __shared__ unsigned short lists[1024 * 16];  // 32 KB, [seg][q][16]
    __shared__ unsigned sthr[256];               // shared per-query threshold
    int b = blockIdx.x >> 3, tile = blockIdx.x & 7;
    int base = b * P_;
    int t = threadIdx.x;
    for (int j = t; j < P_; j += 1024) {
        float x = pos[(base + j) * 3 + 0];
        float y = pos[(base + j) * 3 + 1];
        float z = pos[(base + j) * 3 + 2];
        cloud[j] = make_float4(x, y, z, x * x + y * y + z * z);
    }
    if (t < 256) sthr[t] = 0xFFFFFFFFu;
    __syncthreads();

    int seg = t >> 8, q = t & 255;
    int il = tile * 256 + q;
    float4 Q = cloud[il];
    float nx = -2.f * Q.x, ny = -2.f * Q.y, nz = -2.f * Q.z, qs = Q.w;

    unsigned bu[16];
#pragma unroll
    for (int m = 0; m < 16; m++) bu[m] = 0xFFFFFFFFu;

    int j0 = seg << 9;
    if (seg == (tile >> 1))
        scan_seg<true>(cloud, sthr, j0, il, q, nx, ny, nz, qs, bu);
    else
        scan_seg<false>(cloud, sthr, j0, il, q, nx, ny, nz, qs, bu);

#pragma unroll
    for (int m = 0; m < 16; m++) {
        unsigned v = bu[m];
        lists[t * 16 + m] = (v == 0xFFFFFFFFu) ? (unsigned short)0xFFFFu
                                               : (unsigned short)(v & 0x7FFu);
    }
    __syncthreads();

    if (t >= 256) return;

    // ---- merge: exact distances, stable order ----
    int il2 = tile * 256 + t;
    float4 Q2 = cloud[il2];
    float nx2 = -2.f * Q2.x, ny2 = -2.f * Q2.y, nz2 = -2.f * Q2.z, qs2 = Q2.w;
    float md[16]; int mi[16];
#pragma unroll
    for (int m = 0; m < 16; m++) { md[m] = INFINITY; mi[m] = 0; }
    for (int s = 0; s < 4; s++) {
#pragma unroll
        for (int r = 0; r < 16; r++) {
            int jr = lists[((s << 8) | t) * 16 + r];
            int j = jr & 0x7FF;
            float4 Cm = cloud[j];
            float dm = (jr == 0xFFFF) ? INFINITY : distf(Cm, nx2, ny2, nz2, qs2);
            insert16(md, mi, dm, j);
        }
    }

    // ---- geometry (cov over L=8, 5x QR, dc), positions from LDS ----
    float px = Q2.x, py = Q2.y, pz = Q2.z;
    float cx[K_], cy[K_], cz[K_];
#pragma unroll
    for (int k = 0; k < K_; k++) {
        float4 Cv = cloud[mi[k]];
        cx[k] = Cv.x - px;
        cy[k] = Cv.y - py;
        cz[k] = Cv.z - pz;
    }
    float A[3][3];
    {
        float a00 = 0, a01 = 0, a02 = 0, a11 = 0, a12 = 0, a22 = 0;
#pragma unroll
        for (int l = 0; l < L_; l++) {
            a00 += cx[l] * cx[l]; a01 += cx[l] * cy[l]; a02 += cx[l] * cz[l];
            a11 += cy[l] * cy[l]; a12 += cy[l] * cz[l]; a22 += cz[l] * cz[l];
        }
        A[0][0] = a00; A[0][1] = a01; A[0][2] = a02;
        A[1][0] = a01; A[1][1] = a11; A[1][2] = a12;
        A[2][0] = a02; A[2][1] = a12; A[2][2] = a22;
    }
    float Vt[3][3] = {{1.f, 0.f, 0.f}, {0.f, 1.f, 0.f}, {0.f, 0.f, 1.f}};

    for (int it = 0; it < 5; it++) {
        float M00 = A[0][0], M01 = A[0][1], M02 = A[0][2];
        float M10 = A[1][0], M11 = A[1][1], M12 = A[1][2];
        float M20 = A[2][0], M21 = A[2][1], M22 = A[2][2];
        float tau0 = 0.f, v1 = 0.f, v2 = 0.f;
        float xn2 = M10 * M10 + M20 * M20;
        if (xn2 != 0.f) {
            float beta = -copysignf(sqrtf(M00 * M00 + xn2), M00);
            tau0 = (beta - M00) / beta;
            float inv = 1.f / (M00 - beta);
            v1 = M10 * inv; v2 = M20 * inv;
            float s;
            s = tau0 * (M01 + v1 * M11 + v2 * M21); M01 -= s; M11 -= v1 * s; M21 -= v2 * s;
            s = tau0 * (M02 + v1 * M12 + v2 * M22); M02 -= s; M12 -= v1 * s; M22 -= v2 * s;
            M00 = beta;
        }
        float tau1 = 0.f, u2 = 0.f;
        if (M21 != 0.f) {
            float beta1 = -copysignf(sqrtf(M11 * M11 + M21 * M21), M11);
            tau1 = (beta1 - M11) / beta1;
            u2 = M21 / (M11 - beta1);
            float s = tau1 * (M12 + u2 * M22); M12 -= s; M22 -= u2 * s;
            M11 = beta1;
        }
        float h11 = 1.f - tau1, h12 = -tau1 * u2, h22 = 1.f - tau1 * u2 * u2;
        float Qm[3][3];
        Qm[0][0] = 1.f - tau0;
        Qm[1][0] = -v1 * tau0;
        Qm[2][0] = -v2 * tau0;
        float t1 = tau0 * (v1 * h11 + v2 * h12);
        Qm[0][1] = -t1;
        Qm[1][1] = h11 - v1 * t1;
        Qm[2][1] = h12 - v2 * t1;
        float t2 = tau0 * (v1 * h12 + v2 * h22);
        Qm[0][2] = -t2;
        Qm[1][2] = h12 - v1 * t2;
        Qm[2][2] = h22 - v2 * t2;
        A[0][0] = M00 * Qm[0][0] + M01 * Qm[1][0] + M02 * Qm[2][0];
        A[0][1] = M00 * Qm[0][1] + M01 * Qm[1][1] + M02 * Qm[2][1];
        A[0][2] = M00 * Qm[0][2] + M01 * Qm[1][2] + M02 * Qm[2][2];
        A[1][0] = M11 * Qm[1][0] + M12 * Qm[2][0];
        A[1][1] = M11 * Qm[1][1] + M12 * Qm[2][1];
        A[1][2] = M11 * Qm[1][2] + M12 * Qm[2][2];
        A[2][0] = M22 * Qm[2][0];
        A[2][1] = M22 * Qm[2][1];
        A[2][2] = M22 * Qm[2][2];
        float nv[3][3];
#pragma unroll
        for (int r = 0; r < 3; r++)
#pragma unroll
            for (int c = 0; c < 3; c++)
                nv[r][c] = Vt[r][0] * Qm[0][c] + Vt[r][1] * Qm[1][c] + Vt[r][2] * Qm[2][c];
#pragma unroll
        for (int r = 0; r < 3; r++)
#pragma unroll
            for (int c = 0; c < 3; c++) Vt[r][c] = nv[r][c];
    }

    float s2 = 0.f, mx01 = 0.f, mx2 = 0.f;
#pragma unroll
    for (int k = 0; k < K_; k++) {
        float d0 = cx[k] * Vt[0][0] + cy[k] * Vt[1][0] + cz[k] * Vt[2][0];
        float d1 = cx[k] * Vt[0][1] + cy[k] * Vt[1][1] + cz[k] * Vt[2][1];
        float d2 = cx[k] * Vt[0][2] + cy[k] * Vt[1][2] + cz[k] * Vt[2][2];
        s2 += d2;
        mx01 = fmaxf(mx01, fmaxf(fabsf(d0), fabsf(d1)));
        mx2  = fmaxf(mx2, fabsf(d2));
    }
    float sg = (s2 > 0.f) ? 1.f : ((s2 < 0.f) ? -1.f : 0.f);
    float mx = fmaxf(mx01, (sg == 0.f) ? 0.f : mx2);
    float hs = 0.5f / mx;
    float o[48];
#pragma unroll
    for (int k = 0; k < K_; k++) {
        float d0 = cx[k] * Vt[0][0] + cy[k] * Vt[1][0] + cz[k] * Vt[2][0];
        float d1 = cx[k] * Vt[0][1] + cy[k] * Vt[1][1] + cz[k] * Vt[2][1];
        float d2 = (cx[k] * Vt[0][2] + cy[k] * Vt[1][2] + cz[k] * Vt[2][2]) * sg;
        o[k * 3 + 0] = d0 * hs + 0.5f;
        o[k * 3 + 1] = d1 * hs + 0.5f;
        o[k * 3 + 2] = d2 * hs + 0.5f;
    }
    int i = base + il2;
    float4* row = (float4*)(dcn + (size_t)i * 48);
#pragma unroll
    for (int m = 0; m < 12; m++)
        row[m] = make_float4(o[m * 4 + 0], o[m * 4 + 1], o[m * 4 + 2], o[m * 4 + 3]);
}

// ---------- Kernel 2: trilinear spline gather + out_nondir + BN partials -----
__global__ __launch_bounds__(256) void spline_kernel(const float* __restrict__ dcn,
                                                     const float* __restrict__ w_spline,
                                                     const float* __restrict__ w_root,
                                                     const float* __restrict__ b_spline,
                                                     float* __restrict__ x,
                                                     float* __restrict__ partials) {
    __shared__ float ws_t[F_ * KS3_];   // [f][cell], 32000 B
    __shared__ float red[4][64];
    {
        int f = threadIdx.x & 63;
        for (int c = threadIdx.x >> 6; c < KS3_; c += 4)
            ws_t[f * KS3_ + c] = w_spline[c * 64 + f];
    }
    __syncthreads();
    int wave = threadIdx.x >> 6, f = threadIdx.x & 63;
    const float* wbase = &ws_t[f * KS3_];
    float wr = w_root[f] + b_spline[f];
    float s1 = 0.f, s2 = 0.f;
    for (int p = 0; p < 16; p++) {
        int i = blockIdx.x * 64 + wave * 16 + p;
        const float4* row = (const float4*)(dcn + (size_t)i * 48);
        float pr[48];
#pragma unroll
        for (int m = 0; m < 12; m++) {
            float4 v = row[m];
            pr[m * 4 + 0] = v.x; pr[m * 4 + 1] = v.y;
            pr[m * 4 + 2] = v.z; pr[m * 4 + 3] = v.w;
        }
        float acc = 0.f;
#pragma unroll
        for (int k = 0; k < K_; k++) {
            float p0 = pr[k * 3 + 0] * 4.f;
            float p1 = pr[k * 3 + 1] * 4.f;
            float p2 = pr[k * 3 + 2] * 4.f;
            float i0 = fminf(fmaxf(floorf(p0), 0.f), 3.f);
            float i1 = fminf(fmaxf(floorf(p1), 0.f), 3.f);
            float i2 = fminf(fmaxf(floorf(p2), 0.f), 3.f);
            float f0 = p0 - i0, f1 = p1 - i1, f2 = p2 - i2;
            float g0 = 1.f - f0, g1 = 1.f - f1, g2 = 1.f - f2;
            int c = (int)fmaf(i2, 25.f, fmaf(i1, 5.f, i0));  // cell idx in float
            const float* wp = wbase + c;
            float a0 = wp[0],  a1 = wp[1];
            float b0 = wp[5],  b1v = wp[6];
            float c0 = wp[25], c1 = wp[26];
            float d0 = wp[30], d1 = wp[31];
            float wA = g1 * g2, wB = f1 * g2, wC = g1 * f2, wD = f1 * f2;
            acc = fmaf(wA, fmaf(f0, a1, g0 * a0), acc);
            acc = fmaf(wB, fmaf(f0, b1v, g0 * b0), acc);
            acc = fmaf(wC, fmaf(f0, c1, g0 * c0), acc);
            acc = fmaf(wD, fmaf(f0, d1, g0 * d0), acc);
        }
        float xv = acc * (1.f / 16.f) + wr;
        x[(size_t)i * 64 + f] = xv;
        s1 += xv; s2 += xv * xv;
    }
    red[wave][f] = s1; __syncthreads();
    if (threadIdx.x < 64)
        partials[blockIdx.x * 128 + f] = red[0][f] + red[1][f] + red[2][f] + red[3][f];
    __syncthreads();
    red[wave][f] = s2; __syncthreads();
    if (threadIdx.x < 64)
        partials[blockIdx.x * 128 + 64 + f] = red[0][f] + red[1][f] + red[2][f] + red[3][f];
}

// ----------------------- Kernel 3: BN stats finalize -------------------------
__global__ __launch_bounds__(256) void stats_kernel(const float* __restrict__ partials,
                                                    const float* __restrict__ gamma,
                                                    const float* __restrict__ beta,
                                                    float* __restrict__ stats) {
    __shared__ double red1[256], red2[256];
    int t = threadIdx.x;
    int f = t & 63, g = t >> 6;
    double a0 = 0, a1 = 0, a2 = 0, a3 = 0, q0 = 0, q1 = 0, q2 = 0, q3 = 0;
    for (int b2 = g; b2 < 1024; b2 += 16) {
        a0 += (double)partials[(b2     ) * 128 + f];
        q0 += (double)partials[(b2     ) * 128 + 64 + f];
        a1 += (double)partials[(b2 +  4) * 128 + f];
        q1 += (double)partials[(b2 +  4) * 128 + 64 + f];
        a2 += (double)partials[(b2 +  8) * 128 + f];
        q2 += (double)partials[(b2 +  8) * 128 + 64 + f];
        a3 += (double)partials[(b2 + 12) * 128 + f];
        q3 += (double)partials[(b2 + 12) * 128 + 64 + f];
    }
    red1[t] = (a0 + a1) + (a2 + a3);
    red2[t] = (q0 + q1) + (q2 + q3);
    __syncthreads();
    if (t < 64) {
        double S1 = red1[t] + red1[t + 64] + red1[t + 128] + red1[t + 192];
        double S2 = red2[t] + red2[t + 64] + red2[t + 128] + red2[t + 192];
        double mu = S1 / (double)N_;
        double var = S2 / (double)N_ - mu * mu;
        double scale = (double)gamma[t] / sqrt(var + (double)EPS_);
        double shift = (double)beta[t] - mu * scale;
        stats[t] = (float)scale;
        stats[64 + t] = (float)shift;
    }
}

// -------------- Kernel 4: sigmoid + per-batch-chunk partial pool -------------
__global__ __launch_bounds__(256) void pool_partial_kernel(const float* __restrict__ x,
                                                           const float* __restrict__ stats,
                                                           float* __restrict__ pp) {
    __shared__ float red[4][64];
    int blk = blockIdx.x;            // 32 batches * 32 chunks of 64 rows
    int b = blk >> 5, ch = blk & 31;
    int f = threadIdx.x & 63, w = threadIdx.x >> 6;
    float scale = stats[f], shift = stats[64 + f];
    float acc = 0.f;
    int row0 = b * P_ + ch * 64;
    for (int r = w; r < 64; r += 4) {
        float v = x[(size_t)(row0 + r) * 64 + f];
        float t = fmaf(v, scale, shift);
        acc += __fdividef(1.f, 1.f + __expf(-t));
    }
    red[w][f] = acc; __syncthreads();
    if (threadIdx.x < 64) pp[blk * 64 + f] = red[0][f] + red[1][f] + red[2][f] + red[3][f];
}

// ------------------ Kernel 5: batch means + GEMM1 + ELU ----------------------
__global__ __launch_bounds__(256) void mlp1_kernel(const float* __restrict__ pp,
                                                   const float* __restrict__ w1,
                                                   const float* __restrict__ b1,
                                                   float* __restrict__ y1) {
    __shared__ float ssy[64];
    int b = blockIdx.x, t = threadIdx.x;
    if (t < 64) {
        float s = 0.f;
#pragma unroll
        for (int g = 0; g < 32; g++) s += pp[(b * 32 + g) * 64 + t];
        ssy[t] = s * (1.f / 2048.f);
    }
    __syncthreads();
    float acc = b1[t];
#pragma unroll 8
    for (int c = 0; c < F_; c++) acc = fmaf(ssy[c], w1[c * 256 + t], acc);
    y1[b * 256 + t] = acc > 0.f ? acc : expm1f(acc);
}

// ------------------ Kernel 6: GEMM2 + log_softmax (wave-wide) ----------------
__global__ __launch_bounds__(64) void mlp2_kernel(const float* __restrict__ y1,
                                                  const float* __restrict__ w2,
                                                  const float* __restrict__ b2,
                                                  float* __restrict__ out) {
    int b = blockIdx.x, j = threadIdx.x;
    float acc = -INFINITY;
    if (j < NC_) {
        acc = b2[j];
#pragma unroll 8
        for (int c = 0; c < H_; c++) acc = fmaf(y1[b * 256 + c], w2[c * 40 + j], acc);
    }
    float m = acc;
#pragma unroll
    for (int o = 32; o > 0; o >>= 1) m = fmaxf(m, __shfl_xor(m, o, 64));
    float e = (j < NC_) ? expf(acc - m) : 0.f;
    float s = e;
#pragma unroll
    for (int o = 32; o > 0; o >>= 1) s += __shfl_xor(s, o, 64);
    if (j < NC_) out[b * NC_ + j] = acc - m - logf(s);
}

extern "C" void kernel_launch(void* const* d_in, const int* in_sizes, int n_in,
                              void* d_out, int out_size, void* d_ws, size_t ws_size,
                              hipStream_t stream) {
    const float* pos      = (const float*)d_in[0];
    const float* w_spline = (const float*)d_in[2];
    const float* w_root   = (const float*)d_in[3];
    const float* b_spline = (const float*)d_in[4];
    const float* bn_gamma = (const float*)d_in[5];
    const float* bn_beta  = (const float*)d_in[6];
    const float* w1       = (const float*)d_in[7];
    const float* b1       = (const float*)d_in[8];
    const float* w2       = (const float*)d_in[9];
    const float* b2       = (const float*)d_in[10];
    float* out = (float*)d_out;

    char* ws = (char*)d_ws;
    float* dcn      = (float*)(ws + 0);                    // 12 MB
    float* x        = (float*)(ws + (12u << 20));          // 16 MB
    float* partials = (float*)(ws + (28u << 20));          // 512 KB
    float* stats    = (float*)(ws + (28u << 20) + (512u << 10));               // 4 KB slot
    float* pp       = (float*)(ws + (28u << 20) + (512u << 10) + 4096);        // 256 KB
    float* y1       = (float*)(ws + (28u << 20) + (512u << 10) + 4096 + (256u << 10)); // 32 KB

    knn_geom_kernel<<<B_ * 8, 1024, 0, stream>>>(pos, dcn);
    spline_kernel<<<N_ / 64, 256, 0, stream>>>(dcn, w_spline, w_root, b_spline, x, partials);
    stats_kernel<<<1, 256, 0, stream>>>(partials, bn_gamma, bn_beta, stats);
    pool_partial_kernel<<<B_ * 32, 256, 0, stream>>>(x, stats, pp);
    mlp1_kernel<<<B_, 256, 0, stream>>>(pp, w1, b1, y1);
    mlp2_kernel<<<B_, 64, 0, stream>>>(y1, w2, b2, out);
}